// Round 9
// baseline (555.378 us; speedup 1.0000x reference)
//
#include <hip/hip_runtime.h>
#include <hip/hip_bf16.h>
#include <stdint.h>
#include <math.h>

// ---------------- problem constants ----------------
#define NB    8192
#define INDIM 2048
#define EMB   256
#define H1N   1024
#define H2N   512
#define KCB   1024
#define NLAYER 3
#define HASHN 16384

typedef _Float16 f16x8 __attribute__((ext_vector_type(8)));
typedef _Float16 f16x4 __attribute__((ext_vector_type(4)));
typedef _Float16 f16x2 __attribute__((ext_vector_type(2)));
typedef float    f32x4 __attribute__((ext_vector_type(4)));

#define LO_SCALE 1024.0f
#define LO_INV   (1.0f / 1024.0f)

#define GLD16(g, p) __builtin_amdgcn_global_load_lds( \
    (const __attribute__((address_space(1))) void*)(g), \
    (__attribute__((address_space(3))) void*)(p), 16, 0, 0)

template<int N> __device__ inline void waitv() {
  asm volatile("s_waitcnt vmcnt(%0)" :: "i"(N) : "memory");
}

// ---------------- threefry2x32 (20 rounds) ----------------
__host__ __device__ inline void tf2x32(uint32_t k0, uint32_t k1, uint32_t x0, uint32_t x1,
                                       uint32_t& o0, uint32_t& o1)
{
  const uint32_t ks2 = 0x1BD11BDAu ^ k0 ^ k1;
  uint32_t a = x0 + k0, b = x1 + k1;
#define TF_RND(r) { a += b; b = (b << (r)) | (b >> (32 - (r))); b ^= a; }
  TF_RND(13) TF_RND(15) TF_RND(26) TF_RND(6)
  a += k1; b += ks2 + 1u;
  TF_RND(17) TF_RND(29) TF_RND(16) TF_RND(24)
  a += ks2; b += k0 + 2u;
  TF_RND(13) TF_RND(15) TF_RND(26) TF_RND(6)
  a += k0; b += k1 + 3u;
  TF_RND(17) TF_RND(29) TF_RND(16) TF_RND(24)
  a += k1; b += ks2 + 4u;
  TF_RND(13) TF_RND(15) TF_RND(26) TF_RND(6)
  a += ks2; b += k0 + 5u;
#undef TF_RND
  o0 = a; o1 = b;
}

__device__ inline float blk_reduce_sum(float v, float* sbuf)
{
  const int t = threadIdx.x;
  sbuf[t] = v; __syncthreads();
  for (int s = 128; s > 0; s >>= 1) {
    if (t < s) sbuf[t] += sbuf[t + s];
    __syncthreads();
  }
  float r = sbuf[0];
  __syncthreads();
  return r;
}

__device__ inline float wred(float v)
{
#pragma unroll
  for (int m = 32; m > 0; m >>= 1) v += __shfl_xor(v, m);
  return v;
}

// =================== MFMA GEMM (fp16, split-2) ===================
// C[M,N] = A[M,K] * B[N,K]^T.  A/B given as f16 hi (+ lo*1024 when NS==2).
// NS==2: acc0 += hi*hi; acc1 += hi*lo' + lo'*hi; C = acc0 + acc1/1024.
// OUTMODE: 0 = f32; 1 = f16 hi only; 2 = f32 + f16 split2 (Cs0/Cs1);
//          3 = no C write: fused gumbel-max argmax via atomicMax-u64.
// BM in {64,128,256}; BN fixed 128.
// BM=256: 512 threads / 8 waves (4Mx2N), 3-stage counted-vmcnt pipeline (T3/T4).
// BM=64/128: 256 threads, 2-buffer prefetch with __syncthreads drain.
template<int NS, int OUTMODE, int BM>
__global__ __launch_bounds__(BM == 256 ? 512 : 256) void mgemm(
    const _Float16* __restrict__ A0, const _Float16* __restrict__ A1,
    const _Float16* __restrict__ B0, const _Float16* __restrict__ B1,
    void* __restrict__ Cp, _Float16* __restrict__ Cs0, _Float16* __restrict__ Cs1,
    unsigned long long* __restrict__ amax, const float* __restrict__ cn2l,
    uint32_t gk0, uint32_t gk1,
    int M, int N, int K)
{
  constexpr int WAVES = (BM == 256) ? 8 : 4;
  constexpr int RPR = WAVES * 16;          // rows staged per GLD16 round
  constexpr int AR = BM / RPR;             // A rounds
  constexpr int BR = 128 / RPR;            // B rounds
  constexpr int LPS = NS * (AR + BR);      // global_load_lds issues per stage
  constexpr int JN = (BM == 64) ? 2 : 4;   // col fragments per wave
  constexpr int ASPL = BM * 64;            // bytes per A split
  constexpr int ABYTES = NS * ASPL;
  constexpr int BBYTES = NS * 8192;
  constexpr int BUF = ABYTES + BBYTES;
  constexpr int NBUF = (BM == 256) ? 3 : 2;
  __shared__ __align__(16) char sm[NBUF * BUF];

  // XCD-aware bijective swizzle (all grids here have nwg % 8 == 0)
  const int nwg = gridDim.x * gridDim.y;
  const int bid0 = blockIdx.y * gridDim.x + blockIdx.x;
  const int cpx = nwg >> 3;
  const int swz = (bid0 & 7) * cpx + (bid0 >> 3);
  const int bx = swz % gridDim.x, by = swz / gridDim.x;

  const int tid = threadIdx.x;
  const int w = tid >> 6, l = tid & 63;
  const int wm = (BM == 64) ? 0 : (w >> 1);
  const int wn = (BM == 64) ? w : (w & 1);
  constexpr int WCOL = (BM == 64) ? 32 : 64;  // wave col span
  const size_t brow = (size_t)by * BM;
  const size_t bcol = (size_t)bx * 128;

  // staging (pre-swizzled global source; linear LDS dest)
  const int brow16 = w * 16 + (l >> 2);               // 0..RPR-1
  const int bcol16 = ((l & 3) ^ ((l >> 3) & 3)) * 8;

  const _Float16* gA0 = A0 + (brow + brow16) * (size_t)K + bcol16;
  const _Float16* gA1 = (NS >= 2) ? (A1 + (brow + brow16) * (size_t)K + bcol16) : nullptr;
  const _Float16* gB0 = B0 + (bcol + brow16) * (size_t)K + bcol16;
  const _Float16* gB1 = (NS >= 2) ? (B1 + (bcol + brow16) * (size_t)K + bcol16) : nullptr;

  auto STAGE = [&](int buf, int kk) {
    char* bA = sm + buf * BUF;
    char* bB = bA + ABYTES;
#pragma unroll
    for (int i = 0; i < AR; i++) {
      GLD16(gA0 + (size_t)(i * RPR) * K + kk, bA + i * (RPR * 64) + w * 1024);
      if constexpr (NS >= 2) GLD16(gA1 + (size_t)(i * RPR) * K + kk, bA + ASPL + i * (RPR * 64) + w * 1024);
    }
#pragma unroll
    for (int i = 0; i < BR; i++) {
      GLD16(gB0 + (size_t)(i * RPR) * K + kk, bB + i * (RPR * 64) + w * 1024);
      if constexpr (NS >= 2) GLD16(gB1 + (size_t)(i * RPR) * K + kk, bB + 8192 + i * (RPR * 64) + w * 1024);
    }
  };

  f32x4 acc0[4][JN], acc1[4][JN];
#pragma unroll
  for (int i = 0; i < 4; i++)
#pragma unroll
    for (int j = 0; j < JN; j++) {
      acc0[i][j] = (f32x4){0.f, 0.f, 0.f, 0.f};
      if constexpr (NS >= 2) acc1[i][j] = (f32x4){0.f, 0.f, 0.f, 0.f};
    }

  const int srow = l & 15;
  const int ksel = l >> 4;
  const int sel2 = (srow >> 1) & 3;
  const int fslot16 = (ksel ^ sel2) * 16;

  auto COMPUTE = [&](int buf) {
    const char* smA = sm + buf * BUF;
    const char* smB = smA + ABYTES;
    f16x8 ah[4], al[4];
#pragma unroll
    for (int i = 0; i < 4; i++) {
      const int rb = (wm * 64 + i * 16 + srow) * 64 + fslot16;
      ah[i] = *(const f16x8*)(smA + rb);
      if constexpr (NS >= 2) al[i] = *(const f16x8*)(smA + ASPL + rb);
    }
#pragma unroll
    for (int j = 0; j < JN; j++) {
      const int rb = (wn * WCOL + j * 16 + srow) * 64 + fslot16;
      f16x8 bh = *(const f16x8*)(smB + rb);
      f16x8 bl{};
      if constexpr (NS >= 2) bl = *(const f16x8*)(smB + 8192 + rb);
#pragma unroll
      for (int i = 0; i < 4; i++) {
        acc0[i][j] = __builtin_amdgcn_mfma_f32_16x16x32_f16(ah[i], bh, acc0[i][j], 0, 0, 0);
        if constexpr (NS >= 2) {
          acc1[i][j] = __builtin_amdgcn_mfma_f32_16x16x32_f16(ah[i], bl, acc1[i][j], 0, 0, 0);
          acc1[i][j] = __builtin_amdgcn_mfma_f32_16x16x32_f16(al[i], bh, acc1[i][j], 0, 0, 0);
        }
      }
    }
  };

  if constexpr (BM == 256) {
    // ---- 3-stage counted-vmcnt pipeline: loads stay in flight across barriers ----
    const int kst = K / 32;     // >= 8 for all our shapes
    STAGE(0, 0);
    STAGE(1, 32);
    STAGE(2, 64);
    for (int i = 0; i < kst; ++i) {
      if (i + 2 < kst)      waitv<2 * LPS>();   // wait oldest stage only
      else if (i + 1 < kst) waitv<LPS>();
      else                  waitv<0>();
      __builtin_amdgcn_s_barrier();             // buf i%3 visible to all waves
      __builtin_amdgcn_sched_barrier(0);
      COMPUTE(i % 3);
      __builtin_amdgcn_sched_barrier(0);
      __builtin_amdgcn_s_barrier();             // all waves done reading buf i%3
      if (i + 3 < kst) STAGE(i % 3, (i + 3) * 32);
      __builtin_amdgcn_sched_barrier(0);
    }
    asm volatile("s_waitcnt lgkmcnt(0)" ::: "memory");
  } else {
    // ---- 2-buffer prefetch with drain (2 blocks/CU overlap covers the stall) ----
    STAGE(0, 0);
    __syncthreads();
    int cur = 0;
    for (int k0 = 0; k0 < K; k0 += 32) {
      if (k0 + 32 < K) STAGE(cur ^ 1, k0 + 32);
      COMPUTE(cur);
      __syncthreads();
      cur ^= 1;
    }
  }

  if constexpr (OUTMODE == 3) {
    // ---- fused gumbel-max argmax; global combine via atomicMax on packed u64 ----
    const int rowb = (int)brow + wm * 64 + (l >> 4) * 4;
    const int colb = (int)bcol + wn * 64 + (l & 15);
#pragma unroll
    for (int i = 0; i < 4; i++)
#pragma unroll
      for (int r = 0; r < 4; r++) {
        const int grow = rowb + i * 16 + r;
        float bestv = -INFINITY; int bestj = 0x7fffffff;
#pragma unroll
        for (int j = 0; j < JN; j++) {
          float v = acc0[i][j][r];
          if constexpr (NS >= 2) v += acc1[i][j][r] * LO_INV;
          const int gcol = colb + j * 16;
          const uint32_t idx = (uint32_t)(grow * KCB + gcol);
          uint32_t o0, o1;
          tf2x32(gk0, gk1, 0u, idx, o0, o1);
          const uint32_t bits = o0 ^ o1;
          float f = __uint_as_float((bits >> 9) | 0x3f800000u) - 1.0f;
          float u = fmaxf(f, 1.17549435e-38f);
          float gmb = -__logf(-__logf(u));
          float val = gmb + (2.0f * v - cn2l[gcol]) / 1.25f;
          if (val > bestv || (val == bestv && gcol < bestj)) { bestv = val; bestj = gcol; }
        }
#pragma unroll
        for (int m = 1; m < 16; m <<= 1) {
          float ov = __shfl_xor(bestv, m);
          int oj = __shfl_xor(bestj, m);
          if (ov > bestv || (ov == bestv && oj < bestj)) { bestv = ov; bestj = oj; }
        }
        if ((l & 15) == 0) {
          // sortable-float mapping: monotone u32; low word ~idx => ties pick min idx
          uint32_t mb = __float_as_uint(bestv);
          mb = (mb & 0x80000000u) ? ~mb : (mb | 0x80000000u);
          unsigned long long pk = ((unsigned long long)mb << 32)
                                | (unsigned long long)(uint32_t)(~(uint32_t)bestj);
          atomicMax(amax + grow, pk);
        }
      }
  } else {
    // ---- epilogue: C/D layout col=lane&15, row=(lane>>4)*4+r ----
    const int crow0 = wm * 64 + (l >> 4) * 4;
    const int ccol0 = wn * WCOL + (l & 15);
#pragma unroll
    for (int i = 0; i < 4; i++)
#pragma unroll
      for (int j = 0; j < JN; j++)
#pragma unroll
        for (int r = 0; r < 4; r++) {
          float v = acc0[i][j][r];
          if constexpr (NS >= 2) v += acc1[i][j][r] * LO_INV;
          const size_t row = brow + crow0 + i * 16 + r;
          const size_t col = bcol + ccol0 + j * 16;
          const size_t o = row * N + col;
          if constexpr (OUTMODE == 0) {
            ((float*)Cp)[o] = v;
          } else if constexpr (OUTMODE == 1) {
            ((_Float16*)Cp)[o] = (_Float16)v;
          } else {
            ((float*)Cp)[o] = v;
            _Float16 h = (_Float16)v;
            Cs0[o] = h;
            Cs1[o] = (_Float16)((v - (float)h) * LO_SCALE);
          }
        }
  }
}

// ---------------- fused prep: transposes + x split + codebook conv/norms + amax init ----------------
struct PrepArgs {
  const float* w[6];
  _Float16* t0[6];
  _Float16* t1[6];   // null => NS1
  int K[6], N[6];
  int off[7];
  const float* x;
  _Float16* xh; _Float16* xl;
  const float* cb;
  _Float16* cbh; _Float16* cbl;
  float* cn2;
  unsigned long long* amax;
  int cvtBlocks;
};

__global__ __launch_bounds__(256) void prep_all(PrepArgs P)
{
  __shared__ float shf[33 * 32];
  const int b = blockIdx.x, t = threadIdx.x;

  if (b < P.off[6]) {
    // ---- weight transpose + split convert ----
    int j = 0;
    while (b >= P.off[j + 1]) j++;
    const int lb = b - P.off[j];
    const int K = P.K[j], N = P.N[j];
    const int nbx = N / 32;
    const int nb = (lb % nbx) * 32, kb = (lb / nbx) * 32;
    const float* Wsrc = P.w[j];
    _Float16* T0 = P.t0[j];
    _Float16* T1 = P.t1[j];
    const int tx = t & 31, ty = t >> 5;
#pragma unroll
    for (int i = 0; i < 32; i += 8)
      shf[(ty + i) * 33 + tx] = Wsrc[(size_t)(kb + ty + i) * N + nb + tx];
    __syncthreads();
#pragma unroll
    for (int i = 0; i < 32; i += 8) {
      float v = shf[tx * 33 + ty + i];
      size_t o = (size_t)(nb + ty + i) * K + kb + tx;
      _Float16 h = (_Float16)v;
      T0[o] = h;
      if (T1) T1[o] = (_Float16)((v - (float)h) * LO_SCALE);
    }
  } else if (b < P.off[6] + P.cvtBlocks) {
    // ---- x -> f16 split2 (8 elems/thread) ----
    const int i = ((b - P.off[6]) * 256 + t) * 8;
    float4 va = *(const float4*)(P.x + i);
    float4 vb = *(const float4*)(P.x + i + 4);
    float f[8] = {va.x, va.y, va.z, va.w, vb.x, vb.y, vb.z, vb.w};
    f16x8 hv, lv;
#pragma unroll
    for (int e = 0; e < 8; e++) {
      _Float16 h = (_Float16)f[e];
      hv[e] = h;
      lv[e] = (_Float16)((f[e] - (float)h) * LO_SCALE);
    }
    *(f16x8*)(P.xh + i) = hv;
    *(f16x8*)(P.xl + i) = lv;
  } else if (b < P.off[6] + P.cvtBlocks + NLAYER * KCB) {
    // ---- codebook: split convert + squared norms ----
    const int r = b - P.off[6] - P.cvtBlocks;
    const size_t o = (size_t)r * EMB + t;
    const float v = P.cb[o];
    _Float16 h = (_Float16)v;
    P.cbh[o] = h;
    P.cbl[o] = (_Float16)((v - (float)h) * LO_SCALE);
    float s = blk_reduce_sum(v * v, shf);
    if (t == 0) P.cn2[r] = s;
  } else {
    // ---- amax init (layer 0) ----
    const int i = (b - P.off[6] - P.cvtBlocks - NLAYER * KCB) * 256 + t;
    if (i < NB) P.amax[i] = 0ull;
  }
}

// ---------------- fused SiLU + LayerNorm -> f16 (split2 or plain), vectorized ----------------
// IN16: input is f16 (decoder path), else f32.
template<int NCOL, int NS, int IN16>
__global__ __launch_bounds__(256) void silu_ln(const void* __restrict__ inp,
                                               const float* __restrict__ g,
                                               const float* __restrict__ bta,
                                               _Float16* __restrict__ o0,
                                               _Float16* __restrict__ o1)
{
  constexpr int PT = NCOL / 256;    // 4 or 2
  __shared__ float sb[256];
  const int b = blockIdx.x, t = threadIdx.x;
  const int c0 = t * PT;
  float v[PT];
  if constexpr (IN16) {
    const _Float16* row = (const _Float16*)inp + (size_t)b * NCOL;
    if constexpr (PT == 4) {
      f16x4 xv = *(const f16x4*)(row + c0);
#pragma unroll
      for (int i = 0; i < 4; i++) v[i] = (float)xv[i];
    } else {
      f16x2 xv = *(const f16x2*)(row + c0);
      v[0] = (float)xv[0]; v[1] = (float)xv[1];
    }
  } else {
    const float* row = (const float*)inp + (size_t)b * NCOL;
    if constexpr (PT == 4) {
      float4 xv = *(const float4*)(row + c0);
      v[0] = xv.x; v[1] = xv.y; v[2] = xv.z; v[3] = xv.w;
    } else {
      float2 xv = *(const float2*)(row + c0);
      v[0] = xv.x; v[1] = xv.y;
    }
  }
  float s = 0.f;
#pragma unroll
  for (int i = 0; i < PT; i++) {
    float sv = v[i] / (1.f + expf(-v[i]));
    v[i] = sv; s += sv;
  }
  s = blk_reduce_sum(s, sb);
  const float mu = s / (float)NCOL;
  float q = 0.f;
#pragma unroll
  for (int i = 0; i < PT; i++) { float d = v[i] - mu; q += d * d; }
  q = blk_reduce_sum(q, sb);
  const float inv = 1.f / sqrtf(q / (float)NCOL + 1e-5f);

  float gv[PT], bv[PT];
  if constexpr (PT == 4) {
    float4 g4 = *(const float4*)(g + c0);
    float4 b4 = *(const float4*)(bta + c0);
    gv[0]=g4.x; gv[1]=g4.y; gv[2]=g4.z; gv[3]=g4.w;
    bv[0]=b4.x; bv[1]=b4.y; bv[2]=b4.z; bv[3]=b4.w;
  } else {
    float2 g2 = *(const float2*)(g + c0);
    float2 b2 = *(const float2*)(bta + c0);
    gv[0]=g2.x; gv[1]=g2.y; bv[0]=b2.x; bv[1]=b2.y;
  }
  const size_t ob = (size_t)b * NCOL + c0;
  if constexpr (PT == 4) {
    f16x4 h4, l4;
#pragma unroll
    for (int i = 0; i < 4; i++) {
      float y = (v[i] - mu) * inv * gv[i] + bv[i];
      _Float16 h = (_Float16)y;
      h4[i] = h;
      if constexpr (NS >= 2) l4[i] = (_Float16)((y - (float)h) * LO_SCALE);
    }
    *(f16x4*)(o0 + ob) = h4;
    if constexpr (NS >= 2) *(f16x4*)(o1 + ob) = l4;
  } else {
    f16x2 h2, l2;
#pragma unroll
    for (int i = 0; i < 2; i++) {
      float y = (v[i] - mu) * inv * gv[i] + bv[i];
      _Float16 h = (_Float16)y;
      h2[i] = h;
      if constexpr (NS >= 2) l2[i] = (_Float16)((y - (float)h) * LO_SCALE);
    }
    *(f16x2*)(o0 + ob) = h2;
    if constexpr (NS >= 2) *(f16x2*)(o1 + ob) = l2;
  }
}

// ---------------- wave-per-row: decode argmax + rotation-trick update ----------------
__global__ __launch_bounds__(256) void sample_update(
    unsigned long long* __restrict__ amax,
    const float* __restrict__ cbf,
    float* __restrict__ res, float* __restrict__ esum,
    float* __restrict__ qrow, float* __restrict__ outEn,
    _Float16* __restrict__ r0, _Float16* __restrict__ r1,
    _Float16* __restrict__ esumb, int* __restrict__ ids,
    uint32_t* __restrict__ packed, int layer)
{
  const int t = threadIdx.x, w = t >> 6, l = t & 63;
  const int b = blockIdx.x * 4 + w;

  const unsigned long long pk = amax[b];
  const int id = (int)(~(uint32_t)(pk & 0xFFFFFFFFull));
  if (l == 0) {
    ids[b * NLAYER + layer] = id;
    if (layer == NLAYER - 1)
      packed[b] = (uint32_t)ids[b * NLAYER] | ((uint32_t)ids[b * NLAYER + 1] << 10)
                | ((uint32_t)id << 20);
    else
      amax[b] = 0ull;   // re-init for next layer's dist GEMM
  }

  const size_t base = (size_t)b * EMB + l * 4;
  float4 r4 = *(const float4*)(res + base);
  float4 e4 = *(const float4*)(cbf + (size_t)id * EMB + l * 4);
  float r_[4] = {r4.x, r4.y, r4.z, r4.w};
  float e_[4] = {e4.x, e4.y, e4.z, e4.w};

  float a0 = 0.f, a1 = 0.f;
#pragma unroll
  for (int i = 0; i < 4; i++) { a0 += r_[i] * r_[i]; a1 += e_[i] * e_[i]; }
  const float rn2 = wred(a0), en2 = wred(a1);
  const float rn = sqrtf(rn2), en = sqrtf(en2);
  float u_[4], q_[4], s_[4];
  float a2 = 0.f;
#pragma unroll
  for (int i = 0; i < 4; i++) {
    u_[i] = r_[i] / (rn + 1e-8f);
    q_[i] = e_[i] / (en + 1e-8f);
    s_[i] = u_[i] + q_[i];
    a2 += s_[i] * s_[i];
  }
  const float sn2 = wred(a2);
  const float wn_ = 1.f / fmaxf(sqrtf(sn2), 1e-6f);
  float a3 = 0.f, a4 = 0.f;
#pragma unroll
  for (int i = 0; i < 4; i++) {
    a3 += r_[i] * s_[i] * wn_;
    a4 += r_[i] * u_[i];
  }
  const float rw = wred(a3), ru = wred(a4);
  float eo[4];
  float a5 = 0.f, a6 = 0.f;
#pragma unroll
  for (int i = 0; i < 4; i++) {
    eo[i] = r_[i] - 2.f * rw * (s_[i] * wn_) + 2.f * ru * q_[i];
    a5 += eo[i] * eo[i];
    float dq = r_[i] - e_[i];
    a6 += dq * dq;
  }
  const float eo2 = wred(a5), ql = wred(a6);

  if (l == 0) {
    outEn[b * NLAYER + layer] = sqrtf(eo2);
    if (layer == 0) qrow[b] = 1.25f * ql; else qrow[b] += 1.25f * ql;
  }

  float nr[4];
#pragma unroll
  for (int i = 0; i < 4; i++) nr[i] = r_[i] - eo[i];
  if (layer != NLAYER - 1) {
    *(float4*)(res + base) = make_float4(nr[0], nr[1], nr[2], nr[3]);
    f16x4 h4, l4;
#pragma unroll
    for (int i = 0; i < 4; i++) {
      _Float16 h = (_Float16)nr[i];
      h4[i] = h;
      l4[i] = (_Float16)((nr[i] - (float)h) * LO_SCALE);
    }
    *(f16x4*)(r0 + base) = h4;
    *(f16x4*)(r1 + base) = l4;
  }
  float ns[4];
#pragma unroll
  for (int i = 0; i < 4; i++) ns[i] = (layer == 0) ? eo[i] : esum[base + i] + eo[i];
  if (layer != NLAYER - 1) {
    *(float4*)(esum + base) = make_float4(ns[0], ns[1], ns[2], ns[3]);
  } else {
    f16x4 h4;
#pragma unroll
    for (int i = 0; i < 4; i++) h4[i] = (_Float16)ns[i];
    *(f16x4*)(esumb + base) = h4;
  }
}

// ---------------- wave-per-row: final l2norm + per-row recon (y in f16) ----------------
__global__ __launch_bounds__(256) void l2norm_recon(const _Float16* __restrict__ y,
                                                    const float* __restrict__ x,
                                                    float* __restrict__ recon)
{
  const int t = threadIdx.x, w = t >> 6, l = t & 63;
  const int b = blockIdx.x * 4 + w;
  const _Float16* yr = y + (size_t)b * INDIM;
  const float* xr = x + (size_t)b * INDIM;

  float vy[32], xf[32];
  float ss = 0.f;
#pragma unroll
  for (int i = 0; i < 4; i++) {
    const int c = l * 8 + i * 512;
    f16x8 v8 = *(const f16x8*)(yr + c);
    float4 xa = *(const float4*)(xr + c);
    float4 xb = *(const float4*)(xr + c + 4);
    xf[i*8+0]=xa.x; xf[i*8+1]=xa.y; xf[i*8+2]=xa.z; xf[i*8+3]=xa.w;
    xf[i*8+4]=xb.x; xf[i*8+5]=xb.y; xf[i*8+6]=xb.z; xf[i*8+7]=xb.w;
#pragma unroll
    for (int j = 0; j < 8; j++) { vy[i*8+j] = (float)v8[j]; ss += vy[i*8+j] * vy[i*8+j]; }
  }
  ss = wred(ss);
  const float inv = 1.f / fmaxf(sqrtf(ss), 1e-12f);
  float acc = 0.f;
#pragma unroll
  for (int i = 0; i < 32; i++) {
    float d = vy[i] * inv - xf[i];
    acc += d * d;
  }
  acc = wred(acc);
  if (l == 0) recon[b] = acc;
}

// ---------------- finalize: sums + LDS-hash distinct count (single block) ----------------
// #rows with no later duplicate == #distinct id-triples.
__global__ __launch_bounds__(256) void finalize2(const float* __restrict__ recon,
                                                 const float* __restrict__ qrow,
                                                 const uint32_t* __restrict__ packed,
                                                 float* __restrict__ out)
{
  __shared__ uint32_t tab[HASHN];   // 64 KB
  __shared__ double sd[256];
  __shared__ int    si[256];
  const int t = threadIdx.x;
  for (int i = t; i < HASHN; i += 256) tab[i] = 0xFFFFFFFFu;
  __syncthreads();

  int my = 0;
  double aR = 0.0, aQ = 0.0;
  for (int i = t; i < NB; i += 256) {
    aR += (double)recon[i];
    aQ += (double)qrow[i];
    const uint32_t v = packed[i];
    uint32_t h = (v * 2654435761u) & (HASHN - 1);
    while (true) {
      uint32_t old = atomicCAS(&tab[h], 0xFFFFFFFFu, v);
      if (old == 0xFFFFFFFFu) { my++; break; }
      if (old == v) break;
      h = (h + 1) & (HASHN - 1);
    }
  }
  sd[t] = aR; si[t] = my; __syncthreads();
  for (int s = 128; s > 0; s >>= 1) {
    if (t < s) { sd[t] += sd[t + s]; si[t] += si[t + s]; }
    __syncthreads();
  }
  const double sumR = sd[0]; const int dcnt = si[0]; __syncthreads();
  sd[t] = aQ; __syncthreads();
  for (int s = 128; s > 0; s >>= 1) { if (t < s) sd[t] += sd[t + s]; __syncthreads(); }
  const double sumQ = sd[0];
  if (t == 0) {
    const float rm = (float)(sumR / (double)NB);
    const float ql = (float)sumQ;
    out[0] = rm + ql;
    out[1] = rm;
    out[2] = ql;
    out[3 + NB * NLAYER] = (float)dcnt / (float)NB;
  }
}

// ---------------- host launch ----------------
extern "C" void kernel_launch(void* const* d_in, const int* in_sizes, int n_in,
                              void* d_out, int out_size, void* d_ws, size_t ws_size,
                              hipStream_t stream)
{
  const float* x      = (const float*)d_in[0];
  const float* enc_w1 = (const float*)d_in[1];
  const float* enc_g1 = (const float*)d_in[2];
  const float* enc_b1 = (const float*)d_in[3];
  const float* enc_w2 = (const float*)d_in[4];
  const float* enc_g2 = (const float*)d_in[5];
  const float* enc_b2 = (const float*)d_in[6];
  const float* enc_w3 = (const float*)d_in[7];
  const float* dec_w1 = (const float*)d_in[8];
  const float* dec_g1 = (const float*)d_in[9];
  const float* dec_b1 = (const float*)d_in[10];
  const float* dec_w2 = (const float*)d_in[11];
  const float* dec_g2 = (const float*)d_in[12];
  const float* dec_b2 = (const float*)d_in[13];
  const float* dec_w3 = (const float*)d_in[14];
  const float* codebooks = (const float*)d_in[15];
  float* out = (float*)d_out;

  char* W = (char*)d_ws;
  _Float16* xh   = (_Float16*)(W + 0);          // 32MB, dies after enc1
  _Float16* h1n0 = (_Float16*)(W + 0);          // 16MB
  _Float16* h1n1 = (_Float16*)(W + 16777216);   // 16MB
  _Float16* h2n0 = (_Float16*)(W + 0);          // 8MB
  _Float16* h2n1 = (_Float16*)(W + 8388608);    // 8MB
  _Float16* res0 = (_Float16*)(W + 16777216);   // 4MB  (lives through quant loop)
  _Float16* res1 = (_Float16*)(W + 20971520);   // 4MB
  _Float16* d1n  = (_Float16*)(W + 0);          // 8MB (decoder phase)
  _Float16* d2n  = (_Float16*)(W + 25165824);   // 16MB [24,40)
  _Float16* xl    = (_Float16*)(W + 33554432);  // 32MB, dies after enc1
  float*    h2    = (float*)  (W + 33554432);   // 16MB
  _Float16* d1h   = (_Float16*)(W + 33554432);  // 8MB (dec1 f16 out)
  float*    res32 = (float*)  (W + 50331648);   // 8MB
  float*    esum32= (float*)  (W + 58720256);   // 8MB
  float*    h1 = (float*)    (W + 67108864);    // 32MB
  _Float16* d2h = (_Float16*)(W + 67108864);    // 16MB (dec2 f16 out)
  _Float16* yb = (_Float16*) (W + 67108864);    // 32MB (overwrites d2h after it dies)
  _Float16* w1t0 = (_Float16*)(W + 100663296);  // 4MB
  _Float16* w1t1 = (_Float16*)(W + 104857600);  // 4MB
  _Float16* w2t0 = (_Float16*)(W + 109051904);  // 1MB
  _Float16* w2t1 = (_Float16*)(W + 110100480);  // 1MB
  _Float16* w3t0 = (_Float16*)(W + 111149056);  // 256KB
  _Float16* w3t1 = (_Float16*)(W + 111411200);  // 256KB
  _Float16* dw1t = (_Float16*)(W + 111673344);  // 256KB
  _Float16* dw2t = (_Float16*)(W + 111935488);  // 1MB
  _Float16* dw3t = (_Float16*)(W + 112984064);  // 4MB
  _Float16* cbh  = (_Float16*)(W + 117178368);  // 1.5MB
  _Float16* cbl  = (_Float16*)(W + 118751232);  // 1.5MB
  _Float16* esumb= (_Float16*)(W + 120324096);  // 4MB
  float* cn2   = (float*)(W + 124518400);
  float* recon = (float*)(W + 124534784);
  float* qrow  = (float*)(W + 124567552);
  int*   ids   = (int*)  (W + 124600320);
  uint32_t* packed = (uint32_t*)(W + 124698624);
  unsigned long long* amax = (unsigned long long*)(W + 124850176); // 64KB u64[8192]

  // PRNG keys: jax.random.split(jax.random.key(42), 3), partitionable scheme
  uint32_t key0[NLAYER], key1[NLAYER];
  for (int l = 0; l < NLAYER; l++) tf2x32(0u, 42u, 0u, (uint32_t)l, key0[l], key1[l]);

  dim3 blk(256), blk512(512);
  // ---- fused prep ----
  PrepArgs P;
  P.w[0] = enc_w1; P.t0[0] = w1t0; P.t1[0] = w1t1; P.K[0] = INDIM; P.N[0] = H1N;
  P.w[1] = enc_w2; P.t0[1] = w2t0; P.t1[1] = w2t1; P.K[1] = H1N;   P.N[1] = H2N;
  P.w[2] = enc_w3; P.t0[2] = w3t0; P.t1[2] = w3t1; P.K[2] = H2N;   P.N[2] = EMB;
  P.w[3] = dec_w1; P.t0[3] = dw1t; P.t1[3] = nullptr; P.K[3] = EMB; P.N[3] = H2N;
  P.w[4] = dec_w2; P.t0[4] = dw2t; P.t1[4] = nullptr; P.K[4] = H2N; P.N[4] = H1N;
  P.w[5] = dec_w3; P.t0[5] = dw3t; P.t1[5] = nullptr; P.K[5] = H1N; P.N[5] = INDIM;
  P.off[0] = 0;
  for (int j = 0; j < 6; j++) P.off[j + 1] = P.off[j] + (P.N[j] / 32) * (P.K[j] / 32);
  P.x = x; P.xh = xh; P.xl = xl;
  P.cb = codebooks; P.cbh = cbh; P.cbl = cbl; P.cn2 = cn2;
  P.amax = amax;
  P.cvtBlocks = (NB * INDIM) / 2048;
  const int prepGrid = P.off[6] + P.cvtBlocks + NLAYER * KCB + NB / 256;
  prep_all<<<prepGrid, blk, 0, stream>>>(P);

  // ---- encoder (f16 split2, fp32-class) ----
  mgemm<2,0,256><<<dim3(H1N/128, NB/256), blk512, 0, stream>>>(xh, xl, w1t0, w1t1,
      h1, nullptr, nullptr, nullptr, nullptr, 0u, 0u, NB, H1N, INDIM);
  silu_ln<H1N,2,0><<<NB, blk, 0, stream>>>(h1, enc_g1, enc_b1, h1n0, h1n1);
  mgemm<2,0,128><<<dim3(H2N/128, NB/128), blk, 0, stream>>>(h1n0, h1n1, w2t0, w2t1,
      h2, nullptr, nullptr, nullptr, nullptr, 0u, 0u, NB, H2N, H1N);
  silu_ln<H2N,2,0><<<NB, blk, 0, stream>>>(h2, enc_g2, enc_b2, h2n0, h2n1);
  mgemm<2,2,64><<<dim3(EMB/128, NB/64), blk, 0, stream>>>(h2n0, h2n1, w3t0, w3t1,
      res32, res0, res1, nullptr, nullptr, 0u, 0u, NB, EMB, H2N);

  // ---- quantization (dist GEMM with fused gumbel atomic-argmax) ----
  for (int l = 0; l < NLAYER; l++) {
    const float* cbfl = codebooks + (size_t)l * KCB * EMB;
    const size_t co = (size_t)l * KCB * EMB;
    mgemm<2,3,256><<<dim3(KCB/128, NB/256), blk512, 0, stream>>>(res0, res1,
        cbh + co, cbl + co, nullptr, nullptr, nullptr,
        amax, cn2 + l * KCB, key0[l], key1[l], NB, KCB, EMB);
    sample_update<<<NB/4, blk, 0, stream>>>(amax, cbfl,
        res32, esum32, qrow, out + 3, res0, res1, esumb, ids, packed, l);
  }

  // ---- decoder (f16 single product; f16 intermediates) ----
  mgemm<1,1,128><<<dim3(H2N/128, NB/128), blk, 0, stream>>>(esumb, nullptr, dw1t, nullptr,
      d1h, nullptr, nullptr, nullptr, nullptr, 0u, 0u, NB, H2N, EMB);
  silu_ln<H2N,1,1><<<NB, blk, 0, stream>>>(d1h, dec_g1, dec_b1, d1n, nullptr);
  mgemm<1,1,128><<<dim3(H1N/128, NB/128), blk, 0, stream>>>(d1n, nullptr, dw2t, nullptr,
      d2h, nullptr, nullptr, nullptr, nullptr, 0u, 0u, NB, H1N, H2N);
  silu_ln<H1N,1,1><<<NB, blk, 0, stream>>>(d2h, dec_g2, dec_b2, d2n, nullptr);
  mgemm<1,1,256><<<dim3(INDIM/128, NB/256), blk512, 0, stream>>>(d2n, nullptr, dw3t, nullptr,
      yb, nullptr, nullptr, nullptr, nullptr, 0u, 0u, NB, INDIM, H1N);
  l2norm_recon<<<NB/4, blk, 0, stream>>>(yb, x, recon);

  // ---- scalars + p_unique (LDS hash) ----
  finalize2<<<1, blk, 0, stream>>>(recon, qrow, packed, out);
}

// Round 10
// 553.545 us; speedup vs baseline: 1.0033x; 1.0033x over previous
//
#include <hip/hip_runtime.h>
#include <hip/hip_bf16.h>
#include <stdint.h>
#include <math.h>

// ---------------- problem constants ----------------
#define NB    8192
#define INDIM 2048
#define EMB   256
#define H1N   1024
#define H2N   512
#define KCB   1024
#define NLAYER 3
#define HASHN 16384

typedef _Float16 f16x8 __attribute__((ext_vector_type(8)));
typedef _Float16 f16x4 __attribute__((ext_vector_type(4)));
typedef _Float16 f16x2 __attribute__((ext_vector_type(2)));
typedef float    f32x4 __attribute__((ext_vector_type(4)));

#define LO_SCALE 1024.0f
#define LO_INV   (1.0f / 1024.0f)

#define GLD16(g, p) __builtin_amdgcn_global_load_lds( \
    (const __attribute__((address_space(1))) void*)(g), \
    (__attribute__((address_space(3))) void*)(p), 16, 0, 0)

// ---------------- threefry2x32 (20 rounds) ----------------
__host__ __device__ inline void tf2x32(uint32_t k0, uint32_t k1, uint32_t x0, uint32_t x1,
                                       uint32_t& o0, uint32_t& o1)
{
  const uint32_t ks2 = 0x1BD11BDAu ^ k0 ^ k1;
  uint32_t a = x0 + k0, b = x1 + k1;
#define TF_RND(r) { a += b; b = (b << (r)) | (b >> (32 - (r))); b ^= a; }
  TF_RND(13) TF_RND(15) TF_RND(26) TF_RND(6)
  a += k1; b += ks2 + 1u;
  TF_RND(17) TF_RND(29) TF_RND(16) TF_RND(24)
  a += ks2; b += k0 + 2u;
  TF_RND(13) TF_RND(15) TF_RND(26) TF_RND(6)
  a += k0; b += k1 + 3u;
  TF_RND(17) TF_RND(29) TF_RND(16) TF_RND(24)
  a += k1; b += ks2 + 4u;
  TF_RND(13) TF_RND(15) TF_RND(26) TF_RND(6)
  a += ks2; b += k0 + 5u;
#undef TF_RND
  o0 = a; o1 = b;
}

__device__ inline float blk_reduce_sum(float v, float* sbuf)
{
  const int t = threadIdx.x;
  sbuf[t] = v; __syncthreads();
  for (int s = 128; s > 0; s >>= 1) {
    if (t < s) sbuf[t] += sbuf[t + s];
    __syncthreads();
  }
  float r = sbuf[0];
  __syncthreads();
  return r;
}

__device__ inline float wred(float v)
{
#pragma unroll
  for (int m = 32; m > 0; m >>= 1) v += __shfl_xor(v, m);
  return v;
}

// =================== MFMA GEMM (fp16, split-2, double-buffered drain loop) ===============
// C[M,N] = A[M,K] * B[N,K]^T.  A/B given as f16 hi (+ lo*1024 when NS==2).
// NS==2: acc0 += hi*hi; acc1 += hi*lo' + lo'*hi; C = acc0 + acc1/1024.
// OUTMODE: 0 = f32; 1 = f16 hi only; 2 = f32 + f16 split2 (Cs0/Cs1);
//          3 = no C write: fused gumbel-max argmax via atomicMax-u64.
// BM in {64,128,256}; BN fixed 128. BM=256 => 512 threads / 8 waves (4Mx2N).
// KSPLIT>1: blockIdx.z indexes a K-slice; f32 partials written to Cp + z*M*N (OUTMODE 0).
template<int NS, int OUTMODE, int BM, int KSPLIT = 1>
__global__ __launch_bounds__(BM == 256 ? 512 : 256) void mgemm(
    const _Float16* __restrict__ A0, const _Float16* __restrict__ A1,
    const _Float16* __restrict__ B0, const _Float16* __restrict__ B1,
    void* __restrict__ Cp, _Float16* __restrict__ Cs0, _Float16* __restrict__ Cs1,
    unsigned long long* __restrict__ amax, const float* __restrict__ cn2l,
    uint32_t gk0, uint32_t gk1,
    int M, int N, int K)
{
  constexpr int WAVES = (BM == 256) ? 8 : 4;
  constexpr int RPR = WAVES * 16;          // rows staged per GLD16 round
  constexpr int AR = BM / RPR;             // A rounds
  constexpr int BR = 128 / RPR;            // B rounds
  constexpr int JN = (BM == 64) ? 2 : 4;   // col fragments per wave
  constexpr int ASPL = BM * 64;            // bytes per A split
  constexpr int ABYTES = NS * ASPL;
  constexpr int BBYTES = NS * 8192;
  constexpr int BUF = ABYTES + BBYTES;
  __shared__ __align__(16) char sm[2 * BUF];

  // XCD-aware bijective swizzle per z-slice (x*y grids here are multiples of 8)
  const int gx = gridDim.x, gy = gridDim.y;
  const int nwg = gx * gy;
  const int bid0 = blockIdx.y * gx + blockIdx.x;
  const int cpx = nwg >> 3;
  const int swz = (bid0 & 7) * cpx + (bid0 >> 3);
  const int bx = swz % gx, by = swz / gx;
  const int kidx = (KSPLIT > 1) ? blockIdx.z : 0;
  const int kw = K / KSPLIT;

  const int tid = threadIdx.x;
  const int w = tid >> 6, l = tid & 63;
  const int wm = (BM == 64) ? 0 : (w >> 1);
  const int wn = (BM == 64) ? w : (w & 1);
  constexpr int WCOL = (BM == 64) ? 32 : 64;  // wave col span
  const size_t brow = (size_t)by * BM;
  const size_t bcol = (size_t)bx * 128;

  // staging (pre-swizzled global source; linear LDS dest)
  const int brow16 = w * 16 + (l >> 2);               // 0..RPR-1
  const int bcol16 = ((l & 3) ^ ((l >> 3) & 3)) * 8;

  const _Float16* gA0 = A0 + (brow + brow16) * (size_t)K + kidx * kw + bcol16;
  const _Float16* gA1 = (NS >= 2) ? (A1 + (brow + brow16) * (size_t)K + kidx * kw + bcol16) : nullptr;
  const _Float16* gB0 = B0 + (bcol + brow16) * (size_t)K + kidx * kw + bcol16;
  const _Float16* gB1 = (NS >= 2) ? (B1 + (bcol + brow16) * (size_t)K + kidx * kw + bcol16) : nullptr;

  auto STAGE = [&](int buf, int kk) {
    char* bA = sm + buf * BUF;
    char* bB = bA + ABYTES;
#pragma unroll
    for (int i = 0; i < AR; i++) {
      GLD16(gA0 + (size_t)(i * RPR) * K + kk, bA + i * (RPR * 64) + w * 1024);
      if constexpr (NS >= 2) GLD16(gA1 + (size_t)(i * RPR) * K + kk, bA + ASPL + i * (RPR * 64) + w * 1024);
    }
#pragma unroll
    for (int i = 0; i < BR; i++) {
      GLD16(gB0 + (size_t)(i * RPR) * K + kk, bB + i * (RPR * 64) + w * 1024);
      if constexpr (NS >= 2) GLD16(gB1 + (size_t)(i * RPR) * K + kk, bB + 8192 + i * (RPR * 64) + w * 1024);
    }
  };

  f32x4 acc0[4][JN], acc1[4][JN];
#pragma unroll
  for (int i = 0; i < 4; i++)
#pragma unroll
    for (int j = 0; j < JN; j++) {
      acc0[i][j] = (f32x4){0.f, 0.f, 0.f, 0.f};
      if constexpr (NS >= 2) acc1[i][j] = (f32x4){0.f, 0.f, 0.f, 0.f};
    }

  const int srow = l & 15;
  const int ksel = l >> 4;
  const int sel2 = (srow >> 1) & 3;
  const int fslot16 = (ksel ^ sel2) * 16;

  auto COMPUTE = [&](int buf) {
    const char* smA = sm + buf * BUF;
    const char* smB = smA + ABYTES;
    f16x8 ah[4], al[4];
#pragma unroll
    for (int i = 0; i < 4; i++) {
      const int rb = (wm * 64 + i * 16 + srow) * 64 + fslot16;
      ah[i] = *(const f16x8*)(smA + rb);
      if constexpr (NS >= 2) al[i] = *(const f16x8*)(smA + ASPL + rb);
    }
#pragma unroll
    for (int j = 0; j < JN; j++) {
      const int rb = (wn * WCOL + j * 16 + srow) * 64 + fslot16;
      f16x8 bh = *(const f16x8*)(smB + rb);
      f16x8 bl{};
      if constexpr (NS >= 2) bl = *(const f16x8*)(smB + 8192 + rb);
#pragma unroll
      for (int i = 0; i < 4; i++) {
        acc0[i][j] = __builtin_amdgcn_mfma_f32_16x16x32_f16(ah[i], bh, acc0[i][j], 0, 0, 0);
        if constexpr (NS >= 2) {
          acc1[i][j] = __builtin_amdgcn_mfma_f32_16x16x32_f16(ah[i], bl, acc1[i][j], 0, 0, 0);
          acc1[i][j] = __builtin_amdgcn_mfma_f32_16x16x32_f16(al[i], bh, acc1[i][j], 0, 0, 0);
        }
      }
    }
  };

  // ---- 2-buffer prefetch with drain (proven R8 structure) ----
  STAGE(0, 0);
  __syncthreads();
  int cur = 0;
  for (int k0 = 0; k0 < kw; k0 += 32) {
    if (k0 + 32 < kw) STAGE(cur ^ 1, k0 + 32);
    COMPUTE(cur);
    __syncthreads();
    cur ^= 1;
  }

  if constexpr (OUTMODE == 3) {
    // ---- fused gumbel-max argmax; global combine via atomicMax on packed u64 ----
    const int rowb = (int)brow + wm * 64 + (l >> 4) * 4;
    const int colb = (int)bcol + wn * 64 + (l & 15);
#pragma unroll
    for (int i = 0; i < 4; i++)
#pragma unroll
      for (int r = 0; r < 4; r++) {
        const int grow = rowb + i * 16 + r;
        float bestv = -INFINITY; int bestj = 0x7fffffff;
#pragma unroll
        for (int j = 0; j < JN; j++) {
          float v = acc0[i][j][r];
          if constexpr (NS >= 2) v += acc1[i][j][r] * LO_INV;
          const int gcol = colb + j * 16;
          const uint32_t idx = (uint32_t)(grow * KCB + gcol);
          uint32_t o0, o1;
          tf2x32(gk0, gk1, 0u, idx, o0, o1);
          const uint32_t bits = o0 ^ o1;
          float f = __uint_as_float((bits >> 9) | 0x3f800000u) - 1.0f;
          float u = fmaxf(f, 1.17549435e-38f);
          float gmb = -__logf(-__logf(u));
          float val = gmb + (2.0f * v - cn2l[gcol]) / 1.25f;
          if (val > bestv || (val == bestv && gcol < bestj)) { bestv = val; bestj = gcol; }
        }
#pragma unroll
        for (int m = 1; m < 16; m <<= 1) {
          float ov = __shfl_xor(bestv, m);
          int oj = __shfl_xor(bestj, m);
          if (ov > bestv || (ov == bestv && oj < bestj)) { bestv = ov; bestj = oj; }
        }
        if ((l & 15) == 0) {
          // sortable-float mapping: monotone u32; low word ~idx => ties pick min idx
          uint32_t mb = __float_as_uint(bestv);
          mb = (mb & 0x80000000u) ? ~mb : (mb | 0x80000000u);
          unsigned long long pk = ((unsigned long long)mb << 32)
                                | (unsigned long long)(uint32_t)(~(uint32_t)bestj);
          atomicMax(amax + grow, pk);
        }
      }
  } else {
    // ---- epilogue: C/D layout col=lane&15, row=(lane>>4)*4+r ----
    const int crow0 = wm * 64 + (l >> 4) * 4;
    const int ccol0 = wn * WCOL + (l & 15);
    float* Cw = (float*)Cp + (size_t)kidx * M * N;   // partial slice when KSPLIT>1
#pragma unroll
    for (int i = 0; i < 4; i++)
#pragma unroll
      for (int j = 0; j < JN; j++)
#pragma unroll
        for (int r = 0; r < 4; r++) {
          float v = acc0[i][j][r];
          if constexpr (NS >= 2) v += acc1[i][j][r] * LO_INV;
          const size_t row = brow + crow0 + i * 16 + r;
          const size_t col = bcol + ccol0 + j * 16;
          const size_t o = row * N + col;
          if constexpr (OUTMODE == 0) {
            Cw[o] = v;
          } else if constexpr (OUTMODE == 1) {
            ((_Float16*)Cp)[o] = (_Float16)v;
          } else {
            ((float*)Cp)[o] = v;
            _Float16 h = (_Float16)v;
            Cs0[o] = h;
            Cs1[o] = (_Float16)((v - (float)h) * LO_SCALE);
          }
        }
  }
}

// ---------------- fused prep: transposes + x split + codebook conv/norms + amax init ----------------
struct PrepArgs {
  const float* w[6];
  _Float16* t0[6];
  _Float16* t1[6];   // null => NS1
  int K[6], N[6];
  int off[7];
  const float* x;
  _Float16* xh; _Float16* xl;
  const float* cb;
  _Float16* cbh; _Float16* cbl;
  float* cn2;
  unsigned long long* amax;
  int cvtBlocks;
};

__global__ __launch_bounds__(256) void prep_all(PrepArgs P)
{
  __shared__ float shf[33 * 32];
  const int b = blockIdx.x, t = threadIdx.x;

  if (b < P.off[6]) {
    // ---- weight transpose + split convert ----
    int j = 0;
    while (b >= P.off[j + 1]) j++;
    const int lb = b - P.off[j];
    const int K = P.K[j], N = P.N[j];
    const int nbx = N / 32;
    const int nb = (lb % nbx) * 32, kb = (lb / nbx) * 32;
    const float* Wsrc = P.w[j];
    _Float16* T0 = P.t0[j];
    _Float16* T1 = P.t1[j];
    const int tx = t & 31, ty = t >> 5;
#pragma unroll
    for (int i = 0; i < 32; i += 8)
      shf[(ty + i) * 33 + tx] = Wsrc[(size_t)(kb + ty + i) * N + nb + tx];
    __syncthreads();
#pragma unroll
    for (int i = 0; i < 32; i += 8) {
      float v = shf[tx * 33 + ty + i];
      size_t o = (size_t)(nb + ty + i) * K + kb + tx;
      _Float16 h = (_Float16)v;
      T0[o] = h;
      if (T1) T1[o] = (_Float16)((v - (float)h) * LO_SCALE);
    }
  } else if (b < P.off[6] + P.cvtBlocks) {
    // ---- x -> f16 split2 (8 elems/thread) ----
    const int i = ((b - P.off[6]) * 256 + t) * 8;
    float4 va = *(const float4*)(P.x + i);
    float4 vb = *(const float4*)(P.x + i + 4);
    float f[8] = {va.x, va.y, va.z, va.w, vb.x, vb.y, vb.z, vb.w};
    f16x8 hv, lv;
#pragma unroll
    for (int e = 0; e < 8; e++) {
      _Float16 h = (_Float16)f[e];
      hv[e] = h;
      lv[e] = (_Float16)((f[e] - (float)h) * LO_SCALE);
    }
    *(f16x8*)(P.xh + i) = hv;
    *(f16x8*)(P.xl + i) = lv;
  } else if (b < P.off[6] + P.cvtBlocks + NLAYER * KCB) {
    // ---- codebook: split convert + squared norms ----
    const int r = b - P.off[6] - P.cvtBlocks;
    const size_t o = (size_t)r * EMB + t;
    const float v = P.cb[o];
    _Float16 h = (_Float16)v;
    P.cbh[o] = h;
    P.cbl[o] = (_Float16)((v - (float)h) * LO_SCALE);
    float s = blk_reduce_sum(v * v, shf);
    if (t == 0) P.cn2[r] = s;
  } else {
    // ---- amax init (layer 0) ----
    const int i = (b - P.off[6] - P.cvtBlocks - NLAYER * KCB) * 256 + t;
    if (i < NB) P.amax[i] = 0ull;
  }
}

// ---------------- fused SiLU + LayerNorm -> f16 (split2 or plain), vectorized ----------------
// IN16: input is f16 (decoder path), else f32. ADD2: sum two f32 inputs (split-K combine).
template<int NCOL, int NS, int IN16, int ADD2 = 0>
__global__ __launch_bounds__(256) void silu_ln(const void* __restrict__ inp,
                                               const float* __restrict__ in2,
                                               const float* __restrict__ g,
                                               const float* __restrict__ bta,
                                               _Float16* __restrict__ o0,
                                               _Float16* __restrict__ o1)
{
  constexpr int PT = NCOL / 256;    // 4 or 2
  __shared__ float sb[256];
  const int b = blockIdx.x, t = threadIdx.x;
  const int c0 = t * PT;
  float v[PT];
  if constexpr (IN16) {
    const _Float16* row = (const _Float16*)inp + (size_t)b * NCOL;
    if constexpr (PT == 4) {
      f16x4 xv = *(const f16x4*)(row + c0);
#pragma unroll
      for (int i = 0; i < 4; i++) v[i] = (float)xv[i];
    } else {
      f16x2 xv = *(const f16x2*)(row + c0);
      v[0] = (float)xv[0]; v[1] = (float)xv[1];
    }
  } else {
    const float* row = (const float*)inp + (size_t)b * NCOL;
    if constexpr (PT == 4) {
      float4 xv = *(const float4*)(row + c0);
      v[0] = xv.x; v[1] = xv.y; v[2] = xv.z; v[3] = xv.w;
    } else {
      float2 xv = *(const float2*)(row + c0);
      v[0] = xv.x; v[1] = xv.y;
    }
    if constexpr (ADD2) {
      const float* row2 = in2 + (size_t)b * NCOL;
      if constexpr (PT == 4) {
        float4 yv = *(const float4*)(row2 + c0);
        v[0] += yv.x; v[1] += yv.y; v[2] += yv.z; v[3] += yv.w;
      } else {
        float2 yv = *(const float2*)(row2 + c0);
        v[0] += yv.x; v[1] += yv.y;
      }
    }
  }
  float s = 0.f;
#pragma unroll
  for (int i = 0; i < PT; i++) {
    float sv = v[i] / (1.f + expf(-v[i]));
    v[i] = sv; s += sv;
  }
  s = blk_reduce_sum(s, sb);
  const float mu = s / (float)NCOL;
  float q = 0.f;
#pragma unroll
  for (int i = 0; i < PT; i++) { float d = v[i] - mu; q += d * d; }
  q = blk_reduce_sum(q, sb);
  const float inv = 1.f / sqrtf(q / (float)NCOL + 1e-5f);

  float gv[PT], bv[PT];
  if constexpr (PT == 4) {
    float4 g4 = *(const float4*)(g + c0);
    float4 b4 = *(const float4*)(bta + c0);
    gv[0]=g4.x; gv[1]=g4.y; gv[2]=g4.z; gv[3]=g4.w;
    bv[0]=b4.x; bv[1]=b4.y; bv[2]=b4.z; bv[3]=b4.w;
  } else {
    float2 g2 = *(const float2*)(g + c0);
    float2 b2 = *(const float2*)(bta + c0);
    gv[0]=g2.x; gv[1]=g2.y; bv[0]=b2.x; bv[1]=b2.y;
  }
  const size_t ob = (size_t)b * NCOL + c0;
  if constexpr (PT == 4) {
    f16x4 h4, l4;
#pragma unroll
    for (int i = 0; i < 4; i++) {
      float y = (v[i] - mu) * inv * gv[i] + bv[i];
      _Float16 h = (_Float16)y;
      h4[i] = h;
      if constexpr (NS >= 2) l4[i] = (_Float16)((y - (float)h) * LO_SCALE);
    }
    *(f16x4*)(o0 + ob) = h4;
    if constexpr (NS >= 2) *(f16x4*)(o1 + ob) = l4;
  } else {
    f16x2 h2, l2;
#pragma unroll
    for (int i = 0; i < 2; i++) {
      float y = (v[i] - mu) * inv * gv[i] + bv[i];
      _Float16 h = (_Float16)y;
      h2[i] = h;
      if constexpr (NS >= 2) l2[i] = (_Float16)((y - (float)h) * LO_SCALE);
    }
    *(f16x2*)(o0 + ob) = h2;
    if constexpr (NS >= 2) *(f16x2*)(o1 + ob) = l2;
  }
}

// ---------------- wave-per-row: decode argmax + rotation-trick update ----------------
__global__ __launch_bounds__(256) void sample_update(
    unsigned long long* __restrict__ amax,
    const float* __restrict__ cbf,
    float* __restrict__ res, float* __restrict__ esum,
    float* __restrict__ qrow, float* __restrict__ outEn,
    _Float16* __restrict__ r0, _Float16* __restrict__ r1,
    _Float16* __restrict__ esumb, int* __restrict__ ids,
    uint32_t* __restrict__ packed, int layer)
{
  const int t = threadIdx.x, w = t >> 6, l = t & 63;
  const int b = blockIdx.x * 4 + w;

  const unsigned long long pk = amax[b];
  const int id = (int)(~(uint32_t)(pk & 0xFFFFFFFFull));
  if (l == 0) {
    ids[b * NLAYER + layer] = id;
    if (layer == NLAYER - 1)
      packed[b] = (uint32_t)ids[b * NLAYER] | ((uint32_t)ids[b * NLAYER + 1] << 10)
                | ((uint32_t)id << 20);
    else
      amax[b] = 0ull;   // re-init for next layer's dist GEMM
  }

  const size_t base = (size_t)b * EMB + l * 4;
  float4 r4 = *(const float4*)(res + base);
  float4 e4 = *(const float4*)(cbf + (size_t)id * EMB + l * 4);
  float r_[4] = {r4.x, r4.y, r4.z, r4.w};
  float e_[4] = {e4.x, e4.y, e4.z, e4.w};

  float a0 = 0.f, a1 = 0.f;
#pragma unroll
  for (int i = 0; i < 4; i++) { a0 += r_[i] * r_[i]; a1 += e_[i] * e_[i]; }
  const float rn2 = wred(a0), en2 = wred(a1);
  const float rn = sqrtf(rn2), en = sqrtf(en2);
  float u_[4], q_[4], s_[4];
  float a2 = 0.f;
#pragma unroll
  for (int i = 0; i < 4; i++) {
    u_[i] = r_[i] / (rn + 1e-8f);
    q_[i] = e_[i] / (en + 1e-8f);
    s_[i] = u_[i] + q_[i];
    a2 += s_[i] * s_[i];
  }
  const float sn2 = wred(a2);
  const float wn_ = 1.f / fmaxf(sqrtf(sn2), 1e-6f);
  float a3 = 0.f, a4 = 0.f;
#pragma unroll
  for (int i = 0; i < 4; i++) {
    a3 += r_[i] * s_[i] * wn_;
    a4 += r_[i] * u_[i];
  }
  const float rw = wred(a3), ru = wred(a4);
  float eo[4];
  float a5 = 0.f, a6 = 0.f;
#pragma unroll
  for (int i = 0; i < 4; i++) {
    eo[i] = r_[i] - 2.f * rw * (s_[i] * wn_) + 2.f * ru * q_[i];
    a5 += eo[i] * eo[i];
    float dq = r_[i] - e_[i];
    a6 += dq * dq;
  }
  const float eo2 = wred(a5), ql = wred(a6);

  if (l == 0) {
    outEn[b * NLAYER + layer] = sqrtf(eo2);
    if (layer == 0) qrow[b] = 1.25f * ql; else qrow[b] += 1.25f * ql;
  }

  float nr[4];
#pragma unroll
  for (int i = 0; i < 4; i++) nr[i] = r_[i] - eo[i];
  if (layer != NLAYER - 1) {
    *(float4*)(res + base) = make_float4(nr[0], nr[1], nr[2], nr[3]);
    f16x4 h4, l4;
#pragma unroll
    for (int i = 0; i < 4; i++) {
      _Float16 h = (_Float16)nr[i];
      h4[i] = h;
      l4[i] = (_Float16)((nr[i] - (float)h) * LO_SCALE);
    }
    *(f16x4*)(r0 + base) = h4;
    *(f16x4*)(r1 + base) = l4;
  }
  float ns[4];
#pragma unroll
  for (int i = 0; i < 4; i++) ns[i] = (layer == 0) ? eo[i] : esum[base + i] + eo[i];
  if (layer != NLAYER - 1) {
    *(float4*)(esum + base) = make_float4(ns[0], ns[1], ns[2], ns[3]);
  } else {
    f16x4 h4;
#pragma unroll
    for (int i = 0; i < 4; i++) h4[i] = (_Float16)ns[i];
    *(f16x4*)(esumb + base) = h4;
  }
}

// ---------------- wave-per-row: final l2norm + per-row recon (y in f16) ----------------
__global__ __launch_bounds__(256) void l2norm_recon(const _Float16* __restrict__ y,
                                                    const float* __restrict__ x,
                                                    float* __restrict__ recon)
{
  const int t = threadIdx.x, w = t >> 6, l = t & 63;
  const int b = blockIdx.x * 4 + w;
  const _Float16* yr = y + (size_t)b * INDIM;
  const float* xr = x + (size_t)b * INDIM;

  float vy[32], xf[32];
  float ss = 0.f;
#pragma unroll
  for (int i = 0; i < 4; i++) {
    const int c = l * 8 + i * 512;
    f16x8 v8 = *(const f16x8*)(yr + c);
    float4 xa = *(const float4*)(xr + c);
    float4 xb = *(const float4*)(xr + c + 4);
    xf[i*8+0]=xa.x; xf[i*8+1]=xa.y; xf[i*8+2]=xa.z; xf[i*8+3]=xa.w;
    xf[i*8+4]=xb.x; xf[i*8+5]=xb.y; xf[i*8+6]=xb.z; xf[i*8+7]=xb.w;
#pragma unroll
    for (int j = 0; j < 8; j++) { vy[i*8+j] = (float)v8[j]; ss += vy[i*8+j] * vy[i*8+j]; }
  }
  ss = wred(ss);
  const float inv = 1.f / fmaxf(sqrtf(ss), 1e-12f);
  float acc = 0.f;
#pragma unroll
  for (int i = 0; i < 32; i++) {
    float d = vy[i] * inv - xf[i];
    acc += d * d;
  }
  acc = wred(acc);
  if (l == 0) recon[b] = acc;
}

// ---------------- finalize: sums + LDS-hash distinct count (single block) ----------------
// #rows with no later duplicate == #distinct id-triples.
__global__ __launch_bounds__(256) void finalize2(const float* __restrict__ recon,
                                                 const float* __restrict__ qrow,
                                                 const uint32_t* __restrict__ packed,
                                                 float* __restrict__ out)
{
  __shared__ uint32_t tab[HASHN];   // 64 KB
  __shared__ double sd[256];
  __shared__ int    si[256];
  const int t = threadIdx.x;
  for (int i = t; i < HASHN; i += 256) tab[i] = 0xFFFFFFFFu;
  __syncthreads();

  int my = 0;
  double aR = 0.0, aQ = 0.0;
  for (int i = t; i < NB; i += 256) {
    aR += (double)recon[i];
    aQ += (double)qrow[i];
    const uint32_t v = packed[i];
    uint32_t h = (v * 2654435761u) & (HASHN - 1);
    while (true) {
      uint32_t old = atomicCAS(&tab[h], 0xFFFFFFFFu, v);
      if (old == 0xFFFFFFFFu) { my++; break; }
      if (old == v) break;
      h = (h + 1) & (HASHN - 1);
    }
  }
  sd[t] = aR; si[t] = my; __syncthreads();
  for (int s = 128; s > 0; s >>= 1) {
    if (t < s) { sd[t] += sd[t + s]; si[t] += si[t + s]; }
    __syncthreads();
  }
  const double sumR = sd[0]; const int dcnt = si[0]; __syncthreads();
  sd[t] = aQ; __syncthreads();
  for (int s = 128; s > 0; s >>= 1) { if (t < s) sd[t] += sd[t + s]; __syncthreads(); }
  const double sumQ = sd[0];
  if (t == 0) {
    const float rm = (float)(sumR / (double)NB);
    const float ql = (float)sumQ;
    out[0] = rm + ql;
    out[1] = rm;
    out[2] = ql;
    out[3 + NB * NLAYER] = (float)dcnt / (float)NB;
  }
}

// ---------------- host launch ----------------
extern "C" void kernel_launch(void* const* d_in, const int* in_sizes, int n_in,
                              void* d_out, int out_size, void* d_ws, size_t ws_size,
                              hipStream_t stream)
{
  const float* x      = (const float*)d_in[0];
  const float* enc_w1 = (const float*)d_in[1];
  const float* enc_g1 = (const float*)d_in[2];
  const float* enc_b1 = (const float*)d_in[3];
  const float* enc_w2 = (const float*)d_in[4];
  const float* enc_g2 = (const float*)d_in[5];
  const float* enc_b2 = (const float*)d_in[6];
  const float* enc_w3 = (const float*)d_in[7];
  const float* dec_w1 = (const float*)d_in[8];
  const float* dec_g1 = (const float*)d_in[9];
  const float* dec_b1 = (const float*)d_in[10];
  const float* dec_w2 = (const float*)d_in[11];
  const float* dec_g2 = (const float*)d_in[12];
  const float* dec_b2 = (const float*)d_in[13];
  const float* dec_w3 = (const float*)d_in[14];
  const float* codebooks = (const float*)d_in[15];
  float* out = (float*)d_out;

  char* W = (char*)d_ws;
  _Float16* xh   = (_Float16*)(W + 0);          // 32MB, dies after enc1
  _Float16* h1n0 = (_Float16*)(W + 0);          // 16MB
  _Float16* h1n1 = (_Float16*)(W + 16777216);   // 16MB
  _Float16* h2n0 = (_Float16*)(W + 0);          // 8MB
  _Float16* h2n1 = (_Float16*)(W + 8388608);    // 8MB
  _Float16* res0 = (_Float16*)(W + 16777216);   // 4MB  (lives through quant loop)
  _Float16* res1 = (_Float16*)(W + 20971520);   // 4MB
  _Float16* d1n  = (_Float16*)(W + 0);          // 8MB (decoder phase)
  _Float16* d2n  = (_Float16*)(W + 25165824);   // 16MB [24,40)
  _Float16* xl    = (_Float16*)(W + 33554432);  // 32MB, dies after enc1
  _Float16* d1h   = (_Float16*)(W + 33554432);  // 8MB (dec1 f16 out)
  float*    res32 = (float*)  (W + 50331648);   // 8MB
  float*    esum32= (float*)  (W + 58720256);   // 8MB
  float*    h1 = (float*)    (W + 67108864);    // 32MB
  float*    h2p = (float*)   (W + 67108864);    // 32MB: 2x16MB split-K partials (after h1 dies)
  _Float16* d2h = (_Float16*)(W + 67108864);    // 16MB (dec2 f16 out)
  _Float16* yb = (_Float16*) (W + 67108864);    // 32MB (overwrites d2h after it dies)
  _Float16* w1t0 = (_Float16*)(W + 100663296);  // 4MB
  _Float16* w1t1 = (_Float16*)(W + 104857600);  // 4MB
  _Float16* w2t0 = (_Float16*)(W + 109051904);  // 1MB
  _Float16* w2t1 = (_Float16*)(W + 110100480);  // 1MB
  _Float16* w3t0 = (_Float16*)(W + 111149056);  // 256KB
  _Float16* w3t1 = (_Float16*)(W + 111411200);  // 256KB
  _Float16* dw1t = (_Float16*)(W + 111673344);  // 256KB
  _Float16* dw2t = (_Float16*)(W + 111935488);  // 1MB
  _Float16* dw3t = (_Float16*)(W + 112984064);  // 4MB
  _Float16* cbh  = (_Float16*)(W + 117178368);  // 1.5MB
  _Float16* cbl  = (_Float16*)(W + 118751232);  // 1.5MB
  _Float16* esumb= (_Float16*)(W + 120324096);  // 4MB
  float* cn2   = (float*)(W + 124518400);
  float* recon = (float*)(W + 124534784);
  float* qrow  = (float*)(W + 124567552);
  int*   ids   = (int*)  (W + 124600320);
  uint32_t* packed = (uint32_t*)(W + 124698624);
  unsigned long long* amax = (unsigned long long*)(W + 124850176); // 64KB u64[8192]

  // PRNG keys: jax.random.split(jax.random.key(42), 3), partitionable scheme
  uint32_t key0[NLAYER], key1[NLAYER];
  for (int l = 0; l < NLAYER; l++) tf2x32(0u, 42u, 0u, (uint32_t)l, key0[l], key1[l]);

  dim3 blk(256), blk512(512);
  // ---- fused prep ----
  PrepArgs P;
  P.w[0] = enc_w1; P.t0[0] = w1t0; P.t1[0] = w1t1; P.K[0] = INDIM; P.N[0] = H1N;
  P.w[1] = enc_w2; P.t0[1] = w2t0; P.t1[1] = w2t1; P.K[1] = H1N;   P.N[1] = H2N;
  P.w[2] = enc_w3; P.t0[2] = w3t0; P.t1[2] = w3t1; P.K[2] = H2N;   P.N[2] = EMB;
  P.w[3] = dec_w1; P.t0[3] = dw1t; P.t1[3] = nullptr; P.K[3] = EMB; P.N[3] = H2N;
  P.w[4] = dec_w2; P.t0[4] = dw2t; P.t1[4] = nullptr; P.K[4] = H2N; P.N[4] = H1N;
  P.w[5] = dec_w3; P.t0[5] = dw3t; P.t1[5] = nullptr; P.K[5] = H1N; P.N[5] = INDIM;
  P.off[0] = 0;
  for (int j = 0; j < 6; j++) P.off[j + 1] = P.off[j] + (P.N[j] / 32) * (P.K[j] / 32);
  P.x = x; P.xh = xh; P.xl = xl;
  P.cb = codebooks; P.cbh = cbh; P.cbl = cbl; P.cn2 = cn2;
  P.amax = amax;
  P.cvtBlocks = (NB * INDIM) / 2048;
  const int prepGrid = P.off[6] + P.cvtBlocks + NLAYER * KCB + NB / 256;
  prep_all<<<prepGrid, blk, 0, stream>>>(P);

  // ---- encoder (f16 split2, fp32-class) ----
  mgemm<2,0,256><<<dim3(H1N/128, NB/256), blk512, 0, stream>>>(xh, xl, w1t0, w1t1,
      h1, nullptr, nullptr, nullptr, nullptr, 0u, 0u, NB, H1N, INDIM);
  silu_ln<H1N,2,0><<<NB, blk, 0, stream>>>(h1, nullptr, enc_g1, enc_b1, h1n0, h1n1);
  // enc2: split-K=2 (1 -> 2 blocks/CU), f32 partials combined in silu_ln
  mgemm<2,0,128,2><<<dim3(H2N/128, NB/128, 2), blk, 0, stream>>>(h1n0, h1n1, w2t0, w2t1,
      h2p, nullptr, nullptr, nullptr, nullptr, 0u, 0u, NB, H2N, H1N);
  silu_ln<H2N,2,0,1><<<NB, blk, 0, stream>>>(h2p, h2p + (size_t)NB * H2N,
      enc_g2, enc_b2, h2n0, h2n1);
  mgemm<2,2,64><<<dim3(EMB/128, NB/64), blk, 0, stream>>>(h2n0, h2n1, w3t0, w3t1,
      res32, res0, res1, nullptr, nullptr, 0u, 0u, NB, EMB, H2N);

  // ---- quantization (dist GEMM with fused gumbel atomic-argmax) ----
  for (int l = 0; l < NLAYER; l++) {
    const float* cbfl = codebooks + (size_t)l * KCB * EMB;
    const size_t co = (size_t)l * KCB * EMB;
    mgemm<2,3,256><<<dim3(KCB/128, NB/256), blk512, 0, stream>>>(res0, res1,
        cbh + co, cbl + co, nullptr, nullptr, nullptr,
        amax, cn2 + l * KCB, key0[l], key1[l], NB, KCB, EMB);
    sample_update<<<NB/4, blk, 0, stream>>>(amax, cbfl,
        res32, esum32, qrow, out + 3, res0, res1, esumb, ids, packed, l);
  }

  // ---- decoder (f16 single product; f16 intermediates) ----
  mgemm<1,1,128><<<dim3(H2N/128, NB/128), blk, 0, stream>>>(esumb, nullptr, dw1t, nullptr,
      d1h, nullptr, nullptr, nullptr, nullptr, 0u, 0u, NB, H2N, EMB);
  silu_ln<H2N,1,1><<<NB, blk, 0, stream>>>(d1h, nullptr, dec_g1, dec_b1, d1n, nullptr);
  mgemm<1,1,128><<<dim3(H1N/128, NB/128), blk, 0, stream>>>(d1n, nullptr, dw2t, nullptr,
      d2h, nullptr, nullptr, nullptr, nullptr, 0u, 0u, NB, H1N, H2N);
  silu_ln<H1N,1,1><<<NB, blk, 0, stream>>>(d2h, nullptr, dec_g2, dec_b2, d2n, nullptr);
  mgemm<1,1,256><<<dim3(INDIM/128, NB/256), blk512, 0, stream>>>(d2n, nullptr, dw3t, nullptr,
      yb, nullptr, nullptr, nullptr, nullptr, 0u, 0u, NB, INDIM, H1N);
  l2norm_recon<<<NB/4, blk, 0, stream>>>(yb, x, recon);

  // ---- scalars + p_unique (LDS hash) ----
  finalize2<<<1, blk, 0, stream>>>(recon, qrow, packed, out);
}

// Round 11
// 544.820 us; speedup vs baseline: 1.0194x; 1.0160x over previous
//
#include <hip/hip_runtime.h>
#include <hip/hip_bf16.h>
#include <stdint.h>
#include <math.h>

// ---------------- problem constants ----------------
#define NB    8192
#define INDIM 2048
#define EMB   256
#define H1N   1024
#define H2N   512
#define KCB   1024
#define NLAYER 3
#define HASHN 16384

typedef _Float16 f16x8 __attribute__((ext_vector_type(8)));
typedef _Float16 f16x4 __attribute__((ext_vector_type(4)));
typedef _Float16 f16x2 __attribute__((ext_vector_type(2)));
typedef float    f32x4 __attribute__((ext_vector_type(4)));

#define LO_SCALE 1024.0f
#define LO_INV   (1.0f / 1024.0f)

#define GLD16(g, p) __builtin_amdgcn_global_load_lds( \
    (const __attribute__((address_space(1))) void*)(g), \
    (__attribute__((address_space(3))) void*)(p), 16, 0, 0)

// ---------------- threefry2x32 (20 rounds) ----------------
__host__ __device__ inline void tf2x32(uint32_t k0, uint32_t k1, uint32_t x0, uint32_t x1,
                                       uint32_t& o0, uint32_t& o1)
{
  const uint32_t ks2 = 0x1BD11BDAu ^ k0 ^ k1;
  uint32_t a = x0 + k0, b = x1 + k1;
#define TF_RND(r) { a += b; b = (b << (r)) | (b >> (32 - (r))); b ^= a; }
  TF_RND(13) TF_RND(15) TF_RND(26) TF_RND(6)
  a += k1; b += ks2 + 1u;
  TF_RND(17) TF_RND(29) TF_RND(16) TF_RND(24)
  a += ks2; b += k0 + 2u;
  TF_RND(13) TF_RND(15) TF_RND(26) TF_RND(6)
  a += k0; b += k1 + 3u;
  TF_RND(17) TF_RND(29) TF_RND(16) TF_RND(24)
  a += k1; b += ks2 + 4u;
  TF_RND(13) TF_RND(15) TF_RND(26) TF_RND(6)
  a += ks2; b += k0 + 5u;
#undef TF_RND
  o0 = a; o1 = b;
}

__device__ inline float blk_reduce_sum(float v, float* sbuf)
{
  const int t = threadIdx.x;
  sbuf[t] = v; __syncthreads();
  for (int s = 128; s > 0; s >>= 1) {
    if (t < s) sbuf[t] += sbuf[t + s];
    __syncthreads();
  }
  float r = sbuf[0];
  __syncthreads();
  return r;
}

__device__ inline float wred(float v)
{
#pragma unroll
  for (int m = 32; m > 0; m >>= 1) v += __shfl_xor(v, m);
  return v;
}

// =================== MFMA GEMM (fp16, split-2, double-buffered drain loop) ===============
// C[M,N] = A[M,K] * B[N,K]^T.  A/B given as f16 hi (+ lo*1024 when NS==2).
// NS==2: acc0 += hi*hi; acc1 += hi*lo' + lo'*hi; C = acc0 + acc1/1024.
// OUTMODE: 0 = f32; 1 = f16 hi only; 2 = f32 + f16 split2 (Cs0/Cs1);
//          3 = no C write: fused gumbel-max argmax via atomicMax-u64.
// BM in {64,128,256}; BN fixed 128. BM=256 => 512 threads / 8 waves (4Mx2N).
template<int NS, int OUTMODE, int BM>
__global__ __launch_bounds__(BM == 256 ? 512 : 256) void mgemm(
    const _Float16* __restrict__ A0, const _Float16* __restrict__ A1,
    const _Float16* __restrict__ B0, const _Float16* __restrict__ B1,
    void* __restrict__ Cp, _Float16* __restrict__ Cs0, _Float16* __restrict__ Cs1,
    unsigned long long* __restrict__ amax, const float* __restrict__ cn2l,
    uint32_t gk0, uint32_t gk1,
    int M, int N, int K)
{
  constexpr int WAVES = (BM == 256) ? 8 : 4;
  constexpr int RPR = WAVES * 16;          // rows staged per GLD16 round
  constexpr int AR = BM / RPR;             // A rounds
  constexpr int BR = 128 / RPR;            // B rounds
  constexpr int JN = (BM == 64) ? 2 : 4;   // col fragments per wave
  constexpr int ASPL = BM * 64;            // bytes per A split
  constexpr int ABYTES = NS * ASPL;
  constexpr int BBYTES = NS * 8192;
  constexpr int BUF = ABYTES + BBYTES;
  __shared__ __align__(16) char sm[2 * BUF];

  // XCD-aware bijective swizzle (all grids here have nwg % 8 == 0)
  const int gx = gridDim.x;
  const int nwg = gx * gridDim.y;
  const int bid0 = blockIdx.y * gx + blockIdx.x;
  const int cpx = nwg >> 3;
  const int swz = (bid0 & 7) * cpx + (bid0 >> 3);
  const int bx = swz % gx, by = swz / gx;

  const int tid = threadIdx.x;
  const int w = tid >> 6, l = tid & 63;
  const int wm = (BM == 64) ? 0 : (w >> 1);
  const int wn = (BM == 64) ? w : (w & 1);
  constexpr int WCOL = (BM == 64) ? 32 : 64;  // wave col span
  const size_t brow = (size_t)by * BM;
  const size_t bcol = (size_t)bx * 128;

  // staging (pre-swizzled global source; linear LDS dest)
  const int brow16 = w * 16 + (l >> 2);               // 0..RPR-1
  const int bcol16 = ((l & 3) ^ ((l >> 3) & 3)) * 8;

  const _Float16* gA0 = A0 + (brow + brow16) * (size_t)K + bcol16;
  const _Float16* gA1 = (NS >= 2) ? (A1 + (brow + brow16) * (size_t)K + bcol16) : nullptr;
  const _Float16* gB0 = B0 + (bcol + brow16) * (size_t)K + bcol16;
  const _Float16* gB1 = (NS >= 2) ? (B1 + (bcol + brow16) * (size_t)K + bcol16) : nullptr;

  auto STAGE = [&](int buf, int kk) {
    char* bA = sm + buf * BUF;
    char* bB = bA + ABYTES;
#pragma unroll
    for (int i = 0; i < AR; i++) {
      GLD16(gA0 + (size_t)(i * RPR) * K + kk, bA + i * (RPR * 64) + w * 1024);
      if constexpr (NS >= 2) GLD16(gA1 + (size_t)(i * RPR) * K + kk, bA + ASPL + i * (RPR * 64) + w * 1024);
    }
#pragma unroll
    for (int i = 0; i < BR; i++) {
      GLD16(gB0 + (size_t)(i * RPR) * K + kk, bB + i * (RPR * 64) + w * 1024);
      if constexpr (NS >= 2) GLD16(gB1 + (size_t)(i * RPR) * K + kk, bB + 8192 + i * (RPR * 64) + w * 1024);
    }
  };

  f32x4 acc0[4][JN], acc1[4][JN];
#pragma unroll
  for (int i = 0; i < 4; i++)
#pragma unroll
    for (int j = 0; j < JN; j++) {
      acc0[i][j] = (f32x4){0.f, 0.f, 0.f, 0.f};
      if constexpr (NS >= 2) acc1[i][j] = (f32x4){0.f, 0.f, 0.f, 0.f};
    }

  const int srow = l & 15;
  const int ksel = l >> 4;
  const int sel2 = (srow >> 1) & 3;
  const int fslot16 = (ksel ^ sel2) * 16;

  auto COMPUTE = [&](int buf) {
    const char* smA = sm + buf * BUF;
    const char* smB = smA + ABYTES;
    f16x8 ah[4], al[4];
#pragma unroll
    for (int i = 0; i < 4; i++) {
      const int rb = (wm * 64 + i * 16 + srow) * 64 + fslot16;
      ah[i] = *(const f16x8*)(smA + rb);
      if constexpr (NS >= 2) al[i] = *(const f16x8*)(smA + ASPL + rb);
    }
#pragma unroll
    for (int j = 0; j < JN; j++) {
      const int rb = (wn * WCOL + j * 16 + srow) * 64 + fslot16;
      f16x8 bh = *(const f16x8*)(smB + rb);
      f16x8 bl{};
      if constexpr (NS >= 2) bl = *(const f16x8*)(smB + 8192 + rb);
#pragma unroll
      for (int i = 0; i < 4; i++) {
        acc0[i][j] = __builtin_amdgcn_mfma_f32_16x16x32_f16(ah[i], bh, acc0[i][j], 0, 0, 0);
        if constexpr (NS >= 2) {
          acc1[i][j] = __builtin_amdgcn_mfma_f32_16x16x32_f16(ah[i], bl, acc1[i][j], 0, 0, 0);
          acc1[i][j] = __builtin_amdgcn_mfma_f32_16x16x32_f16(al[i], bh, acc1[i][j], 0, 0, 0);
        }
      }
    }
  };

  // ---- 2-buffer prefetch with drain (proven R8 structure) ----
  STAGE(0, 0);
  __syncthreads();
  int cur = 0;
  for (int k0 = 0; k0 < K; k0 += 32) {
    if (k0 + 32 < K) STAGE(cur ^ 1, k0 + 32);
    COMPUTE(cur);
    __syncthreads();
    cur ^= 1;
  }

  if constexpr (OUTMODE == 3) {
    // ---- fused gumbel-max argmax; global combine via atomicMax on packed u64 ----
    const int rowb = (int)brow + wm * 64 + (l >> 4) * 4;
    const int colb = (int)bcol + wn * 64 + (l & 15);
#pragma unroll
    for (int i = 0; i < 4; i++)
#pragma unroll
      for (int r = 0; r < 4; r++) {
        const int grow = rowb + i * 16 + r;
        float bestv = -INFINITY; int bestj = 0x7fffffff;
#pragma unroll
        for (int j = 0; j < JN; j++) {
          float v = acc0[i][j][r];
          if constexpr (NS >= 2) v += acc1[i][j][r] * LO_INV;
          const int gcol = colb + j * 16;
          const uint32_t idx = (uint32_t)(grow * KCB + gcol);
          uint32_t o0, o1;
          tf2x32(gk0, gk1, 0u, idx, o0, o1);
          const uint32_t bits = o0 ^ o1;
          float f = __uint_as_float((bits >> 9) | 0x3f800000u) - 1.0f;
          float u = fmaxf(f, 1.17549435e-38f);
          float gmb = -__logf(-__logf(u));
          float val = gmb + (2.0f * v - cn2l[gcol]) / 1.25f;
          if (val > bestv || (val == bestv && gcol < bestj)) { bestv = val; bestj = gcol; }
        }
#pragma unroll
        for (int m = 1; m < 16; m <<= 1) {
          float ov = __shfl_xor(bestv, m);
          int oj = __shfl_xor(bestj, m);
          if (ov > bestv || (ov == bestv && oj < bestj)) { bestv = ov; bestj = oj; }
        }
        if ((l & 15) == 0) {
          // sortable-float mapping: monotone u32; low word ~idx => ties pick min idx
          uint32_t mb = __float_as_uint(bestv);
          mb = (mb & 0x80000000u) ? ~mb : (mb | 0x80000000u);
          unsigned long long pk = ((unsigned long long)mb << 32)
                                | (unsigned long long)(uint32_t)(~(uint32_t)bestj);
          atomicMax(amax + grow, pk);
        }
      }
  } else {
    // ---- epilogue: C/D layout col=lane&15, row=(lane>>4)*4+r ----
    const int crow0 = wm * 64 + (l >> 4) * 4;
    const int ccol0 = wn * WCOL + (l & 15);
#pragma unroll
    for (int i = 0; i < 4; i++)
#pragma unroll
      for (int j = 0; j < JN; j++)
#pragma unroll
        for (int r = 0; r < 4; r++) {
          float v = acc0[i][j][r];
          if constexpr (NS >= 2) v += acc1[i][j][r] * LO_INV;
          const size_t row = brow + crow0 + i * 16 + r;
          const size_t col = bcol + ccol0 + j * 16;
          const size_t o = row * N + col;
          if constexpr (OUTMODE == 0) {
            ((float*)Cp)[o] = v;
          } else if constexpr (OUTMODE == 1) {
            ((_Float16*)Cp)[o] = (_Float16)v;
          } else {
            ((float*)Cp)[o] = v;
            _Float16 h = (_Float16)v;
            Cs0[o] = h;
            Cs1[o] = (_Float16)((v - (float)h) * LO_SCALE);
          }
        }
  }
}

// ---------------- fused prep: transposes + x split + codebook conv/norms + amax init ----------------
// All sections vectorized (G13): float4 loads, f16x4 stores.
struct PrepArgs {
  const float* w[6];
  _Float16* t0[6];
  _Float16* t1[6];   // null => NS1
  int K[6], N[6];
  int off[7];
  const float* x;
  _Float16* xh; _Float16* xl;
  const float* cb;
  _Float16* cbh; _Float16* cbl;
  float* cn2;
  unsigned long long* amax;
  int cvtBlocks;
  int cbBlocks;
};

__global__ __launch_bounds__(256) void prep_all(PrepArgs P)
{
  __shared__ float shf[33 * 32];
  const int b = blockIdx.x, t = threadIdx.x;

  if (b < P.off[6]) {
    // ---- weight transpose + split convert (32k x 32n tile, single pass) ----
    int j = 0;
    while (b >= P.off[j + 1]) j++;
    const int lb = b - P.off[j];
    const int K = P.K[j], N = P.N[j];
    const int nbx = N / 32;
    const int nb = (lb % nbx) * 32, kb = (lb / nbx) * 32;
    const float* Wsrc = P.w[j];
    _Float16* T0 = P.t0[j];
    _Float16* T1 = P.t1[j];
    // load: row = t>>3 (0..31), col4 = (t&7)*4 ; float4 per thread
    {
      const int row = t >> 3, c4 = (t & 7) * 4;
      float4 v4 = *(const float4*)&Wsrc[(size_t)(kb + row) * N + nb + c4];
      shf[row * 33 + c4 + 0] = v4.x;
      shf[row * 33 + c4 + 1] = v4.y;
      shf[row * 33 + c4 + 2] = v4.z;
      shf[row * 33 + c4 + 3] = v4.w;
    }
    __syncthreads();
    // write transposed: n = t>>3, k4 = (t&7)*4 ; f16x4 per thread (64B/8-lane group)
    {
      const int n = t >> 3, k4 = (t & 7) * 4;
      f16x4 h4, l4;
#pragma unroll
      for (int e = 0; e < 4; e++) {
        float v = shf[(k4 + e) * 33 + n];
        _Float16 h = (_Float16)v;
        h4[e] = h;
        l4[e] = (_Float16)((v - (float)h) * LO_SCALE);
      }
      const size_t o = (size_t)(nb + n) * K + kb + k4;
      *(f16x4*)&T0[o] = h4;
      if (T1) *(f16x4*)&T1[o] = l4;
    }
  } else if (b < P.off[6] + P.cvtBlocks) {
    // ---- x -> f16 split2 (8 elems/thread) ----
    const int i = ((b - P.off[6]) * 256 + t) * 8;
    float4 va = *(const float4*)(P.x + i);
    float4 vb = *(const float4*)(P.x + i + 4);
    float f[8] = {va.x, va.y, va.z, va.w, vb.x, vb.y, vb.z, vb.w};
    f16x8 hv, lv;
#pragma unroll
    for (int e = 0; e < 8; e++) {
      _Float16 h = (_Float16)f[e];
      hv[e] = h;
      lv[e] = (_Float16)((f[e] - (float)h) * LO_SCALE);
    }
    *(f16x8*)(P.xh + i) = hv;
    *(f16x8*)(P.xl + i) = lv;
  } else if (b < P.off[6] + P.cvtBlocks + P.cbBlocks) {
    // ---- codebook: split convert + squared norms (wave-per-row, float4) ----
    const int b3 = b - P.off[6] - P.cvtBlocks;
    const int w = t >> 6, l = t & 63;
    const int r = b3 * 4 + w;
    const size_t o = (size_t)r * EMB + l * 4;
    float4 v4 = *(const float4*)(P.cb + o);
    float f[4] = {v4.x, v4.y, v4.z, v4.w};
    f16x4 h4, l4;
    float s = 0.f;
#pragma unroll
    for (int e = 0; e < 4; e++) {
      _Float16 h = (_Float16)f[e];
      h4[e] = h;
      l4[e] = (_Float16)((f[e] - (float)h) * LO_SCALE);
      s += f[e] * f[e];
    }
    *(f16x4*)(P.cbh + o) = h4;
    *(f16x4*)(P.cbl + o) = l4;
    s = wred(s);
    if (l == 0) P.cn2[r] = s;
  } else {
    // ---- amax init (layer 0) ----
    const int i = (b - P.off[6] - P.cvtBlocks - P.cbBlocks) * 256 + t;
    if (i < NB) P.amax[i] = 0ull;
  }
}

// ---------------- fused SiLU + LayerNorm -> f16 (split2 or plain), vectorized ----------------
// IN16: input is f16 (decoder path), else f32.
template<int NCOL, int NS, int IN16>
__global__ __launch_bounds__(256) void silu_ln(const void* __restrict__ inp,
                                               const float* __restrict__ g,
                                               const float* __restrict__ bta,
                                               _Float16* __restrict__ o0,
                                               _Float16* __restrict__ o1)
{
  constexpr int PT = NCOL / 256;    // 4 or 2
  __shared__ float sb[256];
  const int b = blockIdx.x, t = threadIdx.x;
  const int c0 = t * PT;
  float v[PT];
  if constexpr (IN16) {
    const _Float16* row = (const _Float16*)inp + (size_t)b * NCOL;
    if constexpr (PT == 4) {
      f16x4 xv = *(const f16x4*)(row + c0);
#pragma unroll
      for (int i = 0; i < 4; i++) v[i] = (float)xv[i];
    } else {
      f16x2 xv = *(const f16x2*)(row + c0);
      v[0] = (float)xv[0]; v[1] = (float)xv[1];
    }
  } else {
    const float* row = (const float*)inp + (size_t)b * NCOL;
    if constexpr (PT == 4) {
      float4 xv = *(const float4*)(row + c0);
      v[0] = xv.x; v[1] = xv.y; v[2] = xv.z; v[3] = xv.w;
    } else {
      float2 xv = *(const float2*)(row + c0);
      v[0] = xv.x; v[1] = xv.y;
    }
  }
  float s = 0.f;
#pragma unroll
  for (int i = 0; i < PT; i++) {
    float sv = v[i] / (1.f + expf(-v[i]));
    v[i] = sv; s += sv;
  }
  s = blk_reduce_sum(s, sb);
  const float mu = s / (float)NCOL;
  float q = 0.f;
#pragma unroll
  for (int i = 0; i < PT; i++) { float d = v[i] - mu; q += d * d; }
  q = blk_reduce_sum(q, sb);
  const float inv = 1.f / sqrtf(q / (float)NCOL + 1e-5f);

  float gv[PT], bv[PT];
  if constexpr (PT == 4) {
    float4 g4 = *(const float4*)(g + c0);
    float4 b4 = *(const float4*)(bta + c0);
    gv[0]=g4.x; gv[1]=g4.y; gv[2]=g4.z; gv[3]=g4.w;
    bv[0]=b4.x; bv[1]=b4.y; bv[2]=b4.z; bv[3]=b4.w;
  } else {
    float2 g2 = *(const float2*)(g + c0);
    float2 b2 = *(const float2*)(bta + c0);
    gv[0]=g2.x; gv[1]=g2.y; bv[0]=b2.x; bv[1]=b2.y;
  }
  const size_t ob = (size_t)b * NCOL + c0;
  if constexpr (PT == 4) {
    f16x4 h4, l4;
#pragma unroll
    for (int i = 0; i < 4; i++) {
      float y = (v[i] - mu) * inv * gv[i] + bv[i];
      _Float16 h = (_Float16)y;
      h4[i] = h;
      if constexpr (NS >= 2) l4[i] = (_Float16)((y - (float)h) * LO_SCALE);
    }
    *(f16x4*)(o0 + ob) = h4;
    if constexpr (NS >= 2) *(f16x4*)(o1 + ob) = l4;
  } else {
    f16x2 h2, l2;
#pragma unroll
    for (int i = 0; i < 2; i++) {
      float y = (v[i] - mu) * inv * gv[i] + bv[i];
      _Float16 h = (_Float16)y;
      h2[i] = h;
      if constexpr (NS >= 2) l2[i] = (_Float16)((y - (float)h) * LO_SCALE);
    }
    *(f16x2*)(o0 + ob) = h2;
    if constexpr (NS >= 2) *(f16x2*)(o1 + ob) = l2;
  }
}

// ---------------- wave-per-row: decode argmax + rotation-trick update ----------------
__global__ __launch_bounds__(256) void sample_update(
    unsigned long long* __restrict__ amax,
    const float* __restrict__ cbf,
    float* __restrict__ res, float* __restrict__ esum,
    float* __restrict__ qrow, float* __restrict__ outEn,
    _Float16* __restrict__ r0, _Float16* __restrict__ r1,
    _Float16* __restrict__ esumb, int* __restrict__ ids,
    uint32_t* __restrict__ packed, int layer)
{
  const int t = threadIdx.x, w = t >> 6, l = t & 63;
  const int b = blockIdx.x * 4 + w;

  const unsigned long long pk = amax[b];
  const int id = (int)(~(uint32_t)(pk & 0xFFFFFFFFull));
  if (l == 0) {
    ids[b * NLAYER + layer] = id;
    if (layer == NLAYER - 1)
      packed[b] = (uint32_t)ids[b * NLAYER] | ((uint32_t)ids[b * NLAYER + 1] << 10)
                | ((uint32_t)id << 20);
    else
      amax[b] = 0ull;   // re-init for next layer's dist GEMM
  }

  const size_t base = (size_t)b * EMB + l * 4;
  float4 r4 = *(const float4*)(res + base);
  float4 e4 = *(const float4*)(cbf + (size_t)id * EMB + l * 4);
  float r_[4] = {r4.x, r4.y, r4.z, r4.w};
  float e_[4] = {e4.x, e4.y, e4.z, e4.w};

  float a0 = 0.f, a1 = 0.f;
#pragma unroll
  for (int i = 0; i < 4; i++) { a0 += r_[i] * r_[i]; a1 += e_[i] * e_[i]; }
  const float rn2 = wred(a0), en2 = wred(a1);
  const float rn = sqrtf(rn2), en = sqrtf(en2);
  float u_[4], q_[4], s_[4];
  float a2 = 0.f;
#pragma unroll
  for (int i = 0; i < 4; i++) {
    u_[i] = r_[i] / (rn + 1e-8f);
    q_[i] = e_[i] / (en + 1e-8f);
    s_[i] = u_[i] + q_[i];
    a2 += s_[i] * s_[i];
  }
  const float sn2 = wred(a2);
  const float wn_ = 1.f / fmaxf(sqrtf(sn2), 1e-6f);
  float a3 = 0.f, a4 = 0.f;
#pragma unroll
  for (int i = 0; i < 4; i++) {
    a3 += r_[i] * s_[i] * wn_;
    a4 += r_[i] * u_[i];
  }
  const float rw = wred(a3), ru = wred(a4);
  float eo[4];
  float a5 = 0.f, a6 = 0.f;
#pragma unroll
  for (int i = 0; i < 4; i++) {
    eo[i] = r_[i] - 2.f * rw * (s_[i] * wn_) + 2.f * ru * q_[i];
    a5 += eo[i] * eo[i];
    float dq = r_[i] - e_[i];
    a6 += dq * dq;
  }
  const float eo2 = wred(a5), ql = wred(a6);

  if (l == 0) {
    outEn[b * NLAYER + layer] = sqrtf(eo2);
    if (layer == 0) qrow[b] = 1.25f * ql; else qrow[b] += 1.25f * ql;
  }

  float nr[4];
#pragma unroll
  for (int i = 0; i < 4; i++) nr[i] = r_[i] - eo[i];
  if (layer != NLAYER - 1) {
    *(float4*)(res + base) = make_float4(nr[0], nr[1], nr[2], nr[3]);
    f16x4 h4, l4;
#pragma unroll
    for (int i = 0; i < 4; i++) {
      _Float16 h = (_Float16)nr[i];
      h4[i] = h;
      l4[i] = (_Float16)((nr[i] - (float)h) * LO_SCALE);
    }
    *(f16x4*)(r0 + base) = h4;
    *(f16x4*)(r1 + base) = l4;
  }
  float ns[4];
#pragma unroll
  for (int i = 0; i < 4; i++) ns[i] = (layer == 0) ? eo[i] : esum[base + i] + eo[i];
  if (layer != NLAYER - 1) {
    *(float4*)(esum + base) = make_float4(ns[0], ns[1], ns[2], ns[3]);
  } else {
    f16x4 h4;
#pragma unroll
    for (int i = 0; i < 4; i++) h4[i] = (_Float16)ns[i];
    *(f16x4*)(esumb + base) = h4;
  }
}

// ---------------- wave-per-row: final l2norm + per-row recon (y in f16) ----------------
__global__ __launch_bounds__(256) void l2norm_recon(const _Float16* __restrict__ y,
                                                    const float* __restrict__ x,
                                                    float* __restrict__ recon)
{
  const int t = threadIdx.x, w = t >> 6, l = t & 63;
  const int b = blockIdx.x * 4 + w;
  const _Float16* yr = y + (size_t)b * INDIM;
  const float* xr = x + (size_t)b * INDIM;

  float vy[32], xf[32];
  float ss = 0.f;
#pragma unroll
  for (int i = 0; i < 4; i++) {
    const int c = l * 8 + i * 512;
    f16x8 v8 = *(const f16x8*)(yr + c);
    float4 xa = *(const float4*)(xr + c);
    float4 xb = *(const float4*)(xr + c + 4);
    xf[i*8+0]=xa.x; xf[i*8+1]=xa.y; xf[i*8+2]=xa.z; xf[i*8+3]=xa.w;
    xf[i*8+4]=xb.x; xf[i*8+5]=xb.y; xf[i*8+6]=xb.z; xf[i*8+7]=xb.w;
#pragma unroll
    for (int j = 0; j < 8; j++) { vy[i*8+j] = (float)v8[j]; ss += vy[i*8+j] * vy[i*8+j]; }
  }
  ss = wred(ss);
  const float inv = 1.f / fmaxf(sqrtf(ss), 1e-12f);
  float acc = 0.f;
#pragma unroll
  for (int i = 0; i < 32; i++) {
    float d = vy[i] * inv - xf[i];
    acc += d * d;
  }
  acc = wred(acc);
  if (l == 0) recon[b] = acc;
}

// ---------------- finalize: sums + LDS-hash distinct count (single block) ----------------
// #rows with no later duplicate == #distinct id-triples.
__global__ __launch_bounds__(256) void finalize2(const float* __restrict__ recon,
                                                 const float* __restrict__ qrow,
                                                 const uint32_t* __restrict__ packed,
                                                 float* __restrict__ out)
{
  __shared__ uint32_t tab[HASHN];   // 64 KB
  __shared__ double sd[256];
  __shared__ int    si[256];
  const int t = threadIdx.x;
  for (int i = t; i < HASHN; i += 256) tab[i] = 0xFFFFFFFFu;
  __syncthreads();

  int my = 0;
  double aR = 0.0, aQ = 0.0;
  for (int i = t; i < NB; i += 256) {
    aR += (double)recon[i];
    aQ += (double)qrow[i];
    const uint32_t v = packed[i];
    uint32_t h = (v * 2654435761u) & (HASHN - 1);
    while (true) {
      uint32_t old = atomicCAS(&tab[h], 0xFFFFFFFFu, v);
      if (old == 0xFFFFFFFFu) { my++; break; }
      if (old == v) break;
      h = (h + 1) & (HASHN - 1);
    }
  }
  sd[t] = aR; si[t] = my; __syncthreads();
  for (int s = 128; s > 0; s >>= 1) {
    if (t < s) { sd[t] += sd[t + s]; si[t] += si[t + s]; }
    __syncthreads();
  }
  const double sumR = sd[0]; const int dcnt = si[0]; __syncthreads();
  sd[t] = aQ; __syncthreads();
  for (int s = 128; s > 0; s >>= 1) { if (t < s) sd[t] += sd[t + s]; __syncthreads(); }
  const double sumQ = sd[0];
  if (t == 0) {
    const float rm = (float)(sumR / (double)NB);
    const float ql = (float)sumQ;
    out[0] = rm + ql;
    out[1] = rm;
    out[2] = ql;
    out[3 + NB * NLAYER] = (float)dcnt / (float)NB;
  }
}

// ---------------- host launch ----------------
extern "C" void kernel_launch(void* const* d_in, const int* in_sizes, int n_in,
                              void* d_out, int out_size, void* d_ws, size_t ws_size,
                              hipStream_t stream)
{
  const float* x      = (const float*)d_in[0];
  const float* enc_w1 = (const float*)d_in[1];
  const float* enc_g1 = (const float*)d_in[2];
  const float* enc_b1 = (const float*)d_in[3];
  const float* enc_w2 = (const float*)d_in[4];
  const float* enc_g2 = (const float*)d_in[5];
  const float* enc_b2 = (const float*)d_in[6];
  const float* enc_w3 = (const float*)d_in[7];
  const float* dec_w1 = (const float*)d_in[8];
  const float* dec_g1 = (const float*)d_in[9];
  const float* dec_b1 = (const float*)d_in[10];
  const float* dec_w2 = (const float*)d_in[11];
  const float* dec_g2 = (const float*)d_in[12];
  const float* dec_b2 = (const float*)d_in[13];
  const float* dec_w3 = (const float*)d_in[14];
  const float* codebooks = (const float*)d_in[15];
  float* out = (float*)d_out;

  char* W = (char*)d_ws;
  _Float16* xh   = (_Float16*)(W + 0);          // 32MB, dies after enc1
  _Float16* h1n0 = (_Float16*)(W + 0);          // 16MB
  _Float16* h1n1 = (_Float16*)(W + 16777216);   // 16MB
  _Float16* h2n0 = (_Float16*)(W + 0);          // 8MB
  _Float16* h2n1 = (_Float16*)(W + 8388608);    // 8MB
  _Float16* res0 = (_Float16*)(W + 16777216);   // 4MB  (lives through quant loop)
  _Float16* res1 = (_Float16*)(W + 20971520);   // 4MB
  _Float16* d1n  = (_Float16*)(W + 0);          // 8MB (decoder phase)
  _Float16* d2n  = (_Float16*)(W + 25165824);   // 16MB [24,40)
  _Float16* xl    = (_Float16*)(W + 33554432);  // 32MB, dies after enc1
  float*    h2    = (float*)  (W + 33554432);   // 16MB (enc2 f32 out; then dies)
  _Float16* d1h   = (_Float16*)(W + 33554432);  // 8MB (dec1 f16 out, decoder phase)
  float*    res32 = (float*)  (W + 50331648);   // 8MB
  float*    esum32= (float*)  (W + 58720256);   // 8MB
  float*    h1 = (float*)    (W + 67108864);    // 32MB
  _Float16* d2h = (_Float16*)(W + 67108864);    // 16MB (dec2 f16 out)
  _Float16* yb = (_Float16*) (W + 67108864);    // 32MB (overwrites d2h after it dies)
  _Float16* w1t0 = (_Float16*)(W + 100663296);  // 4MB
  _Float16* w1t1 = (_Float16*)(W + 104857600);  // 4MB
  _Float16* w2t0 = (_Float16*)(W + 109051904);  // 1MB
  _Float16* w2t1 = (_Float16*)(W + 110100480);  // 1MB
  _Float16* w3t0 = (_Float16*)(W + 111149056);  // 256KB
  _Float16* w3t1 = (_Float16*)(W + 111411200);  // 256KB
  _Float16* dw1t = (_Float16*)(W + 111673344);  // 256KB
  _Float16* dw2t = (_Float16*)(W + 111935488);  // 1MB
  _Float16* dw3t = (_Float16*)(W + 112984064);  // 4MB
  _Float16* cbh  = (_Float16*)(W + 117178368);  // 1.5MB
  _Float16* cbl  = (_Float16*)(W + 118751232);  // 1.5MB
  _Float16* esumb= (_Float16*)(W + 120324096);  // 4MB
  float* cn2   = (float*)(W + 124518400);
  float* recon = (float*)(W + 124534784);
  float* qrow  = (float*)(W + 124567552);
  int*   ids   = (int*)  (W + 124600320);
  uint32_t* packed = (uint32_t*)(W + 124698624);
  unsigned long long* amax = (unsigned long long*)(W + 124850176); // 64KB u64[8192]

  // PRNG keys: jax.random.split(jax.random.key(42), 3), partitionable scheme
  uint32_t key0[NLAYER], key1[NLAYER];
  for (int l = 0; l < NLAYER; l++) tf2x32(0u, 42u, 0u, (uint32_t)l, key0[l], key1[l]);

  dim3 blk(256), blk512(512);
  // ---- fused prep (vectorized) ----
  PrepArgs P;
  P.w[0] = enc_w1; P.t0[0] = w1t0; P.t1[0] = w1t1; P.K[0] = INDIM; P.N[0] = H1N;
  P.w[1] = enc_w2; P.t0[1] = w2t0; P.t1[1] = w2t1; P.K[1] = H1N;   P.N[1] = H2N;
  P.w[2] = enc_w3; P.t0[2] = w3t0; P.t1[2] = w3t1; P.K[2] = H2N;   P.N[2] = EMB;
  P.w[3] = dec_w1; P.t0[3] = dw1t; P.t1[3] = nullptr; P.K[3] = EMB; P.N[3] = H2N;
  P.w[4] = dec_w2; P.t0[4] = dw2t; P.t1[4] = nullptr; P.K[4] = H2N; P.N[4] = H1N;
  P.w[5] = dec_w3; P.t0[5] = dw3t; P.t1[5] = nullptr; P.K[5] = H1N; P.N[5] = INDIM;
  P.off[0] = 0;
  for (int j = 0; j < 6; j++) P.off[j + 1] = P.off[j] + (P.N[j] / 32) * (P.K[j] / 32);
  P.x = x; P.xh = xh; P.xl = xl;
  P.cb = codebooks; P.cbh = cbh; P.cbl = cbl; P.cn2 = cn2;
  P.amax = amax;
  P.cvtBlocks = (NB * INDIM) / 2048;
  P.cbBlocks = (NLAYER * KCB) / 4;
  const int prepGrid = P.off[6] + P.cvtBlocks + P.cbBlocks + NB / 256;
  prep_all<<<prepGrid, blk, 0, stream>>>(P);

  // ---- encoder (f16 split2, fp32-class) ----
  mgemm<2,0,256><<<dim3(H1N/128, NB/256), blk512, 0, stream>>>(xh, xl, w1t0, w1t1,
      h1, nullptr, nullptr, nullptr, nullptr, 0u, 0u, NB, H1N, INDIM);
  silu_ln<H1N,2,0><<<NB, blk, 0, stream>>>(h1, enc_g1, enc_b1, h1n0, h1n1);
  mgemm<2,0,128><<<dim3(H2N/128, NB/128), blk, 0, stream>>>(h1n0, h1n1, w2t0, w2t1,
      h2, nullptr, nullptr, nullptr, nullptr, 0u, 0u, NB, H2N, H1N);
  silu_ln<H2N,2,0><<<NB, blk, 0, stream>>>(h2, enc_g2, enc_b2, h2n0, h2n1);
  mgemm<2,2,64><<<dim3(EMB/128, NB/64), blk, 0, stream>>>(h2n0, h2n1, w3t0, w3t1,
      res32, res0, res1, nullptr, nullptr, 0u, 0u, NB, EMB, H2N);

  // ---- quantization (dist GEMM with fused gumbel atomic-argmax) ----
  for (int l = 0; l < NLAYER; l++) {
    const float* cbfl = codebooks + (size_t)l * KCB * EMB;
    const size_t co = (size_t)l * KCB * EMB;
    mgemm<2,3,256><<<dim3(KCB/128, NB/256), blk512, 0, stream>>>(res0, res1,
        cbh + co, cbl + co, nullptr, nullptr, nullptr,
        amax, cn2 + l * KCB, key0[l], key1[l], NB, KCB, EMB);
    sample_update<<<NB/4, blk, 0, stream>>>(amax, cbfl,
        res32, esum32, qrow, out + 3, res0, res1, esumb, ids, packed, l);
  }

  // ---- decoder (f16 single product; f16 intermediates) ----
  mgemm<1,1,128><<<dim3(H2N/128, NB/128), blk, 0, stream>>>(esumb, nullptr, dw1t, nullptr,
      d1h, nullptr, nullptr, nullptr, nullptr, 0u, 0u, NB, H2N, EMB);
  silu_ln<H2N,1,1><<<NB, blk, 0, stream>>>(d1h, dec_g1, dec_b1, d1n, nullptr);
  mgemm<1,1,128><<<dim3(H1N/128, NB/128), blk, 0, stream>>>(d1n, nullptr, dw2t, nullptr,
      d2h, nullptr, nullptr, nullptr, nullptr, 0u, 0u, NB, H1N, H2N);
  silu_ln<H1N,1,1><<<NB, blk, 0, stream>>>(d2h, nullptr ? nullptr : dec_g2, dec_b2, d2n, nullptr);
  mgemm<1,1,256><<<dim3(INDIM/128, NB/256), blk512, 0, stream>>>(d2n, nullptr, dw3t, nullptr,
      yb, nullptr, nullptr, nullptr, nullptr, 0u, 0u, NB, INDIM, H1N);
  l2norm_recon<<<NB/4, blk, 0, stream>>>(yb, x, recon);

  // ---- scalars + p_unique (LDS hash) ----
  finalize2<<<1, blk, 0, stream>>>(recon, qrow, packed, out);
}